// Round 3
// baseline (1094.344 us; speedup 1.0000x reference)
//
#include <hip/hip_runtime.h>

typedef short bf16x8 __attribute__((ext_vector_type(8)));
typedef float f32x4 __attribute__((ext_vector_type(4)));

// ---------- bf16 helpers ----------
__device__ __forceinline__ unsigned short f2bf(float f) {
    unsigned u = __float_as_uint(f);
    u += 0x7fffu + ((u >> 16) & 1u);   // round-to-nearest-even
    return (unsigned short)(u >> 16);
}
__device__ __forceinline__ float bflo(unsigned u) { return __uint_as_float(u << 16); }
__device__ __forceinline__ float bfhi(unsigned u) { return __uint_as_float(u & 0xffff0000u); }

// =================== bucketed CSR build (bucket = dst>>8, 256 nodes) ===================

// count edges per bucket (LDS histogram -> global atomic)
__global__ __launch_bounds__(256) void kb_count(const int* __restrict__ dst, int E, int nb,
                                                int chunk, int* __restrict__ total) {
    __shared__ int h[512];
    for (int i = threadIdx.x; i < 512; i += 256) h[i] = 0;
    __syncthreads();
    int e0 = blockIdx.x * chunk, e1 = min(e0 + chunk, E);
    for (int e = e0 + threadIdx.x; e < e1; e += 256) atomicAdd(&h[dst[e] >> 8], 1);
    __syncthreads();
    for (int b = threadIdx.x; b < nb; b += 256) if (h[b]) atomicAdd(&total[b], h[b]);
}

// exclusive scan of bucket totals -> bbase; cursor = bbase
__global__ __launch_bounds__(512) void kb_base(const int* __restrict__ total, int nb,
                                               int* __restrict__ bbase, int* __restrict__ cursor) {
    __shared__ int s[512];
    int t = threadIdx.x;
    int v = (t < nb) ? total[t] : 0;
    s[t] = v; __syncthreads();
    for (int off = 1; off < 512; off <<= 1) {
        int x = (t >= off) ? s[t - off] : 0;
        __syncthreads();
        s[t] += x;
        __syncthreads();
    }
    if (t < nb) { int e = s[t] - v; bbase[t] = e; cursor[t] = e; }
}

// scatter edges into bucket-grouped record array (region-local writes)
__global__ __launch_bounds__(256) void kb_scatter(const int* __restrict__ src,
                                                  const int* __restrict__ dst, int E, int chunk,
                                                  int* __restrict__ cursor,
                                                  int2* __restrict__ rec) {
    int e0 = blockIdx.x * chunk, e1 = min(e0 + chunk, E);
    for (int e = e0 + threadIdx.x; e < e1; e += 256) {
        int s = src[e], d = dst[e];
        int pos = atomicAdd(&cursor[d >> 8], 1);
        rec[pos] = make_int2(s, d);
    }
}

// per-bucket degree count via LDS (cursor[] now holds bucket end)
__global__ __launch_bounds__(256) void kb_deg(const int2* __restrict__ rec,
                                              const int* __restrict__ bbase,
                                              const int* __restrict__ bend,
                                              int* __restrict__ deg, int N) {
    __shared__ int dc[256];
    int b = blockIdx.x, t = threadIdx.x;
    dc[t] = 0; __syncthreads();
    int r0 = bbase[b], r1 = bend[b];
    for (int i = r0 + t; i < r1; i += 256) atomicAdd(&dc[rec[i].y & 255], 1);
    __syncthreads();
    int gn = b * 256 + t;
    if (gn < N) deg[gn] = dc[t];
}

__global__ __launch_bounds__(256) void k_dinv(const int* __restrict__ deg, int N,
                                              float* __restrict__ dinv) {
    int i = blockIdx.x * 256 + threadIdx.x;
    if (i < N) dinv[i] = rsqrtf((float)(deg[i] + 1));
}

// ---------- 3-kernel exclusive scan of PADDED deg -> rowptr ----------
__global__ __launch_bounds__(256) void k_scan_part(const int* __restrict__ deg, int N,
                                                   int* __restrict__ part) {
    int base = blockIdx.x * 1024 + threadIdx.x * 4;
    int s = 0;
#pragma unroll
    for (int i = 0; i < 4; ++i) {
        int idx = base + i;
        if (idx < N) s += (deg[idx] + 7) & ~7;
    }
    __shared__ int red[256];
    red[threadIdx.x] = s; __syncthreads();
    for (int off = 128; off > 0; off >>= 1) {
        if (threadIdx.x < off) red[threadIdx.x] += red[threadIdx.x + off];
        __syncthreads();
    }
    if (threadIdx.x == 0) part[blockIdx.x] = red[0];
}
__global__ void k_scan_mid(int* part, int nb) {
    if (threadIdx.x == 0 && blockIdx.x == 0) {
        int run = 0;
        for (int i = 0; i < nb; ++i) { int t = part[i]; part[i] = run; run += t; }
    }
}
__global__ __launch_bounds__(256) void k_scan_final(const int* __restrict__ deg, int N,
                                                    const int* __restrict__ part,
                                                    int* __restrict__ rowptr) {
    int t = threadIdx.x;
    int base = blockIdx.x * 1024 + t * 4;
    int v[4]; int s = 0;
#pragma unroll
    for (int i = 0; i < 4; ++i) {
        int idx = base + i;
        v[i] = (idx < N) ? ((deg[idx] + 7) & ~7) : 0;
        s += v[i];
    }
    __shared__ int sc[256];
    sc[t] = s; __syncthreads();
    for (int off = 1; off < 256; off <<= 1) {
        int x = (t >= off) ? sc[t - off] : 0;
        __syncthreads();
        sc[t] += x;
        __syncthreads();
    }
    int excl = sc[t] - s + part[blockIdx.x];
#pragma unroll
    for (int i = 0; i < 4; ++i) {
        int idx = base + i;
        if (idx < N) { rowptr[idx] = excl; excl += v[i]; }
    }
}

// per-bucket CSR placement via LDS cursors (csr pre-zeroed; pads stay {0,0})
__global__ __launch_bounds__(256) void kb_place(const int2* __restrict__ rec,
                                                const int* __restrict__ bbase,
                                                const int* __restrict__ bend,
                                                const int* __restrict__ rowptr,
                                                const float* __restrict__ dinv,
                                                int2* __restrict__ csr, int N) {
    __shared__ int cur[256];
    int b = blockIdx.x, t = threadIdx.x;
    int gn = b * 256 + t;
    cur[t] = (gn < N) ? rowptr[gn] : 0;
    __syncthreads();
    int r0 = bbase[b], r1 = bend[b];
    for (int i = r0 + t; i < r1; i += 256) {
        int2 rc = rec[i];
        int pos = atomicAdd(&cur[rc.y & 255], 1);
        float w = dinv[rc.x] * dinv[rc.y];
        csr[pos] = make_int2(rc.x, __float_as_int(w));
    }
}

// =================== W prep: bf16 A-fragment layout ===================
// Wt[f*512 + lane*8 + j] = bf16(W[(kc*32 + (lane>>4)*8 + j)*128 + nt*16 + (lane&15)]),  f = kc*8+nt
__global__ __launch_bounds__(256) void k_wprep(const float* __restrict__ W,
                                               unsigned short* __restrict__ Wt) {
    int t = blockIdx.x * 256 + threadIdx.x;   // 2048 = 32 frags * 64 lanes
    if (t >= 2048) return;
    int f = t >> 6, lane = t & 63;
    int kc = f >> 3, nt = f & 7;
    int kbase = kc * 32 + (lane >> 4) * 8;
    int n = nt * 16 + (lane & 15);
    unsigned short t8[8];
#pragma unroll
    for (int j = 0; j < 8; ++j) t8[j] = f2bf(W[(size_t)(kbase + j) * 128 + n]);
    unsigned short* o = &Wt[(size_t)t * 8];
    *(ushort4*)&o[0] = *(ushort4*)&t8[0];
    *(ushort4*)&o[4] = *(ushort4*)&t8[4];
}

// =================== MFMA GEMM: Hout(bf16) = act(X) @ W ===================
// block: 256 thr = 4 waves; tile 64 rows x 128 cols; wave w handles rows [w*16, w*16+16)
__global__ __launch_bounds__(256) void k_gemm(const void* __restrict__ Xv,
                                              const unsigned short* __restrict__ Wt,
                                              const float* __restrict__ scale,
                                              const float* __restrict__ shift,
                                              unsigned short* __restrict__ Hout,
                                              int N, int xbf16) {
    __shared__ unsigned short sX[64 * 136];   // 17.4 KB, stride 136 breaks bank conflicts
    const int tid = threadIdx.x;
    const int rowBase = blockIdx.x * 64;

    if (!xbf16) {
        const float* X = (const float*)Xv;
#pragma unroll
        for (int i = 0; i < 8; ++i) {
            int f4 = tid + 256 * i;          // 2048 float4 = 64 rows * 32
            int r = f4 >> 5; int k4 = (f4 & 31) * 4;
            int gr = rowBase + r;
            float4 v = make_float4(0.f, 0.f, 0.f, 0.f);
            if (gr < N) v = *(const float4*)&X[(size_t)gr * 128 + k4];
            ushort4 p;
            p.x = f2bf(v.x); p.y = f2bf(v.y); p.z = f2bf(v.z); p.w = f2bf(v.w);
            *(ushort4*)&sX[r * 136 + k4] = p;
        }
    } else {
        const int4* X = (const int4*)Xv;     // bf16 rows: 16 int4 per row
#pragma unroll
        for (int i = 0; i < 4; ++i) {
            int f8 = tid + 256 * i;          // 1024 int4 = 64 rows * 16
            int r = f8 >> 4; int k8 = (f8 & 15) * 8;
            int gr = rowBase + r;
            int4 u = make_int4(0, 0, 0, 0);
            if (gr < N) u = X[(size_t)gr * 16 + (f8 & 15)];
            float fv[8] = { bflo(u.x), bfhi(u.x), bflo(u.y), bfhi(u.y),
                            bflo(u.z), bfhi(u.z), bflo(u.w), bfhi(u.w) };
            unsigned short t8[8];
#pragma unroll
            for (int j = 0; j < 8; ++j)
                t8[j] = f2bf(fmaxf(fmaf(fv[j], scale[k8 + j], shift[k8 + j]), 0.f));
            *(ushort4*)&sX[r * 136 + k8]     = *(ushort4*)&t8[0];
            *(ushort4*)&sX[r * 136 + k8 + 4] = *(ushort4*)&t8[4];
        }
    }
    __syncthreads();

    const int lane = tid & 63, wave = tid >> 6;
    const int m = lane & 15, q = lane >> 4;
    const int rowOff = (wave * 16 + m) * 136 + q * 8;
    f32x4 acc[8];
#pragma unroll
    for (int nt = 0; nt < 8; ++nt) acc[nt] = (f32x4){0.f, 0.f, 0.f, 0.f};
    const bf16x8* WtF = (const bf16x8*)Wt;
#pragma unroll
    for (int kc = 0; kc < 4; ++kc) {
        bf16x8 xb = *(const bf16x8*)&sX[rowOff + kc * 32];
#pragma unroll
        for (int nt = 0; nt < 8; ++nt) {
            bf16x8 wa = WtF[(kc * 8 + nt) * 64 + lane];
            acc[nt] = __builtin_amdgcn_mfma_f32_16x16x32_bf16(wa, xb, acc[nt], 0, 0, 0);
        }
    }
    int grow = rowBase + wave * 16 + m;
    if (grow < N) {
#pragma unroll
        for (int nt = 0; nt < 8; ++nt) {
            ushort4 p;
            p.x = f2bf(acc[nt][0]); p.y = f2bf(acc[nt][1]);
            p.z = f2bf(acc[nt][2]); p.w = f2bf(acc[nt][3]);
            *(ushort4*)&Hout[(size_t)grow * 128 + nt * 16 + q * 4] = p;
        }
    }
}

// =================== aggregation: pad-to-8, clamp-free, bf16 in / bf16 out ===================
__global__ __launch_bounds__(256) void k_agg(const unsigned short* __restrict__ H,
                                             const int* __restrict__ rowptr,
                                             const int* __restrict__ deg,
                                             const int2* __restrict__ csr,
                                             const float* __restrict__ dinv,
                                             const float* __restrict__ bias,
                                             unsigned* __restrict__ out, int N) {
    int wave = threadIdx.x >> 6;
    int lane = threadIdx.x & 63;
    int node = blockIdx.x * 4 + wave;
    if (node >= N) return;
    const unsigned* Hu = (const unsigned*)H;
    int start = rowptr[node];
    int pd = (deg[node] + 7) & ~7;
    float a0 = 0.f, a1 = 0.f;
    const int4* cp = (const int4*)(csr + start);   // start is a multiple of 8 -> 64B aligned
    for (int j = 0; j < pd; j += 8) {
        int4 q0 = cp[0], q1 = cp[1], q2 = cp[2], q3 = cp[3];
        cp += 4;
        unsigned u0 = Hu[(size_t)q0.x * 64 + lane];
        unsigned u1 = Hu[(size_t)q0.z * 64 + lane];
        unsigned u2 = Hu[(size_t)q1.x * 64 + lane];
        unsigned u3 = Hu[(size_t)q1.z * 64 + lane];
        unsigned u4 = Hu[(size_t)q2.x * 64 + lane];
        unsigned u5 = Hu[(size_t)q2.z * 64 + lane];
        unsigned u6 = Hu[(size_t)q3.x * 64 + lane];
        unsigned u7 = Hu[(size_t)q3.z * 64 + lane];
        float w0 = __int_as_float(q0.y), w1 = __int_as_float(q0.w);
        float w2 = __int_as_float(q1.y), w3 = __int_as_float(q1.w);
        float w4 = __int_as_float(q2.y), w5 = __int_as_float(q2.w);
        float w6 = __int_as_float(q3.y), w7 = __int_as_float(q3.w);
        a0 = fmaf(w0, bflo(u0), a0); a1 = fmaf(w0, bfhi(u0), a1);
        a0 = fmaf(w1, bflo(u1), a0); a1 = fmaf(w1, bfhi(u1), a1);
        a0 = fmaf(w2, bflo(u2), a0); a1 = fmaf(w2, bfhi(u2), a1);
        a0 = fmaf(w3, bflo(u3), a0); a1 = fmaf(w3, bfhi(u3), a1);
        a0 = fmaf(w4, bflo(u4), a0); a1 = fmaf(w4, bfhi(u4), a1);
        a0 = fmaf(w5, bflo(u5), a0); a1 = fmaf(w5, bfhi(u5), a1);
        a0 = fmaf(w6, bflo(u6), a0); a1 = fmaf(w6, bfhi(u6), a1);
        a0 = fmaf(w7, bflo(u7), a0); a1 = fmaf(w7, bfhi(u7), a1);
    }
    { // self loop
        float dn = dinv[node];
        float w = dn * dn;
        unsigned u = Hu[(size_t)node * 64 + lane];
        a0 = fmaf(w, bflo(u), a0);
        a1 = fmaf(w, bfhi(u), a1);
    }
    float2 bv = ((const float2*)bias)[lane];
    a0 += bv.x; a1 += bv.y;
    out[(size_t)node * 64 + lane] = (unsigned)f2bf(a0) | ((unsigned)f2bf(a1) << 16);
}

// ---------- BN column stats over bf16 buffer ----------
__global__ __launch_bounds__(256) void k_stats(const unsigned* __restrict__ Bu, int N,
                                               float* __restrict__ S1,
                                               float* __restrict__ S2) {
    int c2 = threadIdx.x & 63;
    int rh = threadIdx.x >> 6;
    float s1a = 0.f, s2a = 0.f, s1b = 0.f, s2b = 0.f;
    for (int r = blockIdx.x * 4 + rh; r < N; r += gridDim.x * 4) {
        unsigned u = Bu[(size_t)r * 64 + c2];
        float va = bflo(u), vb = bfhi(u);
        s1a += va; s2a = fmaf(va, va, s2a);
        s1b += vb; s2b = fmaf(vb, vb, s2b);
    }
    atomicAdd(&S1[2 * c2], s1a); atomicAdd(&S2[2 * c2], s2a);
    atomicAdd(&S1[2 * c2 + 1], s1b); atomicAdd(&S2[2 * c2 + 1], s2b);
}

__global__ void k_bnfinal(const float* __restrict__ S1, const float* __restrict__ S2,
                          const float* __restrict__ g, const float* __restrict__ be,
                          float* __restrict__ scale, float* __restrict__ shift,
                          float invN) {
    int c = threadIdx.x;
    if (c >= 128) return;
    float mu = S1[c] * invN;
    float var = S2[c] * invN - mu * mu;
    float sc = g[c] * rsqrtf(var + 1e-5f);
    scale[c] = sc;
    shift[c] = fmaf(-mu, sc, be[c]);
}

// ---------- per-graph histogram of batch ----------
__global__ __launch_bounds__(256) void k_hist(const int* __restrict__ batch, int N,
                                              int* __restrict__ gcnt) {
    __shared__ int h[64];
    if (threadIdx.x < 64) h[threadIdx.x] = 0;
    __syncthreads();
    for (int i = blockIdx.x * 256 + threadIdx.x; i < N; i += gridDim.x * 256)
        atomicAdd(&h[batch[i]], 1);
    __syncthreads();
    if (threadIdx.x < 64 && h[threadIdx.x]) atomicAdd(&gcnt[threadIdx.x], h[threadIdx.x]);
}

// ---------- pool: pooled[g] += relu(bn2(B[r])) (batch sorted; bf16 input) ----------
__global__ __launch_bounds__(256) void k_pool(const unsigned* __restrict__ Bu,
                                              const float* __restrict__ scale,
                                              const float* __restrict__ shift,
                                              const int* __restrict__ batch, int N,
                                              int rpb, float* __restrict__ pooled) {
    int c2 = threadIdx.x & 63;
    int rh = threadIdx.x >> 6;
    int r0 = blockIdx.x * rpb;
    int r1 = min(r0 + rpb, N);
    float sca = scale[2 * c2], sha = shift[2 * c2];
    float scb = scale[2 * c2 + 1], shb = shift[2 * c2 + 1];
    float aa = 0.f, ab = 0.f; int cur = -1;
    for (int r = r0 + rh; r < r1; r += 4) {
        int g = batch[r];
        if (g != cur) {
            if (cur >= 0) {
                atomicAdd(&pooled[cur * 128 + 2 * c2], aa);
                atomicAdd(&pooled[cur * 128 + 2 * c2 + 1], ab);
            }
            aa = ab = 0.f; cur = g;
        }
        unsigned u = Bu[(size_t)r * 64 + c2];
        aa += fmaxf(fmaf(bflo(u), sca, sha), 0.f);
        ab += fmaxf(fmaf(bfhi(u), scb, shb), 0.f);
    }
    if (cur >= 0) {
        atomicAdd(&pooled[cur * 128 + 2 * c2], aa);
        atomicAdd(&pooled[cur * 128 + 2 * c2 + 1], ab);
    }
}

// ---------- FC ----------
__global__ __launch_bounds__(256) void k_fc(const float* __restrict__ pooled,
                                            const int* __restrict__ gcnt,
                                            const float* __restrict__ Wfc,
                                            const float* __restrict__ bfc,
                                            float* __restrict__ out) {
    int idx = blockIdx.x * 256 + threadIdx.x;
    if (idx >= 64 * 32) return;
    int g = idx >> 5, o = idx & 31;
    float inv = 1.f / fmaxf((float)gcnt[g], 1.f);
    float acc = bfc[o];
    for (int k = 0; k < 128; ++k)
        acc = fmaf(pooled[g * 128 + k] * inv, Wfc[k * 32 + o], acc);
    out[idx] = acc;
}

extern "C" void kernel_launch(void* const* d_in, const int* in_sizes, int n_in,
                              void* d_out, int out_size, void* d_ws, size_t ws_size,
                              hipStream_t stream) {
    const float* x    = (const float*)d_in[0];
    const int*  eidx  = (const int*)d_in[1];
    const int*  batch = (const int*)d_in[2];
    const float* W0 = (const float*)d_in[3];
    const float* b0 = (const float*)d_in[4];
    const float* g0 = (const float*)d_in[5];
    const float* be0 = (const float*)d_in[6];
    const float* W1 = (const float*)d_in[7];
    const float* b1 = (const float*)d_in[8];
    const float* g1 = (const float*)d_in[9];
    const float* be1 = (const float*)d_in[10];
    const float* Wfc = (const float*)d_in[11];
    const float* bfc = (const float*)d_in[12];
    float* out = (float*)d_out;

    const int N = in_sizes[0] / 128;
    const int E = in_sizes[1] / 2;
    const int* esrc = eidx;
    const int* edst = eidx + E;
    const int NB = (N + 255) >> 8;               // buckets of 256 nodes (<=512)
    const size_t paddedE = (size_t)E + 7 * (size_t)N;

    // ---- workspace carve-up ----
    char* base = (char*)d_ws;
    size_t off = 0;
    auto take = [&](size_t bytes) -> char* {
        char* p = base + off;
        off = (off + bytes + 255) & ~(size_t)255;
        return p;
    };
    unsigned short* hA = (unsigned short*)take((size_t)N * 128 * 2); // bf16 h; aliased as rec
    int2* rec = (int2*)hA;                                           // bucket records (dead before gemm1)
    unsigned* B = (unsigned*)take((size_t)N * 64 * 4);               // bf16-packed agg buffer
    int2* csr   = (int2*)take(paddedE * 8);
    int* rowptr = (int*)take((size_t)N * 4);
    int* deg    = (int*)take((size_t)N * 4);
    float* dinv = (float*)take((size_t)N * 4);
    char* zeroA0 = base + off;
    int* total  = (int*)take(512 * 4);
    size_t zeroA_bytes = (size_t)((base + off) - zeroA0);
    int* bbase  = (int*)take(512 * 4);
    int* cursor = (int*)take(512 * 4);
    int* part   = (int*)take(1024 * 4);
    unsigned short* W0t = (unsigned short*)take(16384 * 2);
    unsigned short* W1t = (unsigned short*)take(16384 * 2);
    char* zeroB0 = base + off;
    float* S1a = (float*)take(128 * 4);
    float* S2a = (float*)take(128 * 4);
    float* S1b = (float*)take(128 * 4);
    float* S2b = (float*)take(128 * 4);
    float* pooled = (float*)take(64 * 128 * 4);
    int*   gcnt   = (int*)take(64 * 4);
    size_t zeroB_bytes = (size_t)((base + off) - zeroB0);
    float* scale1 = (float*)take(128 * 4);
    float* shift1 = (float*)take(128 * 4);
    float* scale2 = (float*)take(128 * 4);
    float* shift2 = (float*)take(128 * 4);
    (void)ws_size; (void)n_in; (void)out_size;

    hipMemsetAsync(total, 0, zeroA_bytes, stream);
    hipMemsetAsync(zeroB0, 0, zeroB_bytes, stream);
    hipMemsetAsync(csr, 0, paddedE * 8, stream);   // pad entries -> {src=0, w=0}

    // weight prep (tiny)
    k_wprep<<<8, 256, 0, stream>>>(W0, W0t);
    k_wprep<<<8, 256, 0, stream>>>(W1, W1t);

    // ---- bucketed CSR build ----
    const int CH = (E + 511) / 512;
    kb_count<<<512, 256, 0, stream>>>(edst, E, NB, CH, total);
    kb_base<<<1, 512, 0, stream>>>(total, NB, bbase, cursor);
    kb_scatter<<<512, 256, 0, stream>>>(esrc, edst, E, CH, cursor, rec);
    kb_deg<<<NB, 256, 0, stream>>>(rec, bbase, cursor, deg, N);   // cursor now = bucket end
    k_dinv<<<(N + 255) / 256, 256, 0, stream>>>(deg, N, dinv);
    const int nbScan = (N + 1023) / 1024;
    k_scan_part<<<nbScan, 256, 0, stream>>>(deg, N, part);
    k_scan_mid<<<1, 64, 0, stream>>>(part, nbScan);
    k_scan_final<<<nbScan, 256, 0, stream>>>(deg, N, part, rowptr);
    kb_place<<<NB, 256, 0, stream>>>(rec, bbase, cursor, rowptr, dinv, csr, N);

    const int gGemm = (N + 63) / 64;
    const int gAgg  = (N + 3) / 4;
    const float invN = 1.0f / (float)N;

    // layer 1
    k_gemm<<<gGemm, 256, 0, stream>>>(x, W0t, scale1, shift1, hA, N, 0);
    k_agg<<<gAgg, 256, 0, stream>>>(hA, rowptr, deg, csr, dinv, b0, B, N);
    k_stats<<<256, 256, 0, stream>>>(B, N, S1a, S2a);
    k_bnfinal<<<1, 128, 0, stream>>>(S1a, S2a, g0, be0, scale1, shift1, invN);

    // layer 2 (BN1+ReLU fused into GEMM2's staging)
    k_gemm<<<gGemm, 256, 0, stream>>>(B, W1t, scale1, shift1, hA, N, 1);
    k_agg<<<gAgg, 256, 0, stream>>>(hA, rowptr, deg, csr, dinv, b1, B, N);
    k_stats<<<256, 256, 0, stream>>>(B, N, S1b, S2b);
    k_bnfinal<<<1, 128, 0, stream>>>(S1b, S2b, g1, be1, scale2, shift2, invN);

    // pool (BN2+ReLU fused) + FC
    k_hist<<<256, 256, 0, stream>>>(batch, N, gcnt);
    const int rpb = (N + 511) / 512;
    k_pool<<<(N + rpb - 1) / rpb, 256, 0, stream>>>(B, scale2, shift2, batch, N, rpb, pooled);
    k_fc<<<8, 256, 0, stream>>>(pooled, gcnt, Wfc, bfc, out);
}

// Round 4
// 546.655 us; speedup vs baseline: 2.0019x; 2.0019x over previous
//
#include <hip/hip_runtime.h>

typedef short bf16x8 __attribute__((ext_vector_type(8)));
typedef float f32x4 __attribute__((ext_vector_type(4)));

#define NBLK 512   // scatter blocks (fixed for deterministic two-level offsets)

// ---------- bf16 helpers ----------
__device__ __forceinline__ unsigned short f2bf(float f) {
    unsigned u = __float_as_uint(f);
    u += 0x7fffu + ((u >> 16) & 1u);   // round-to-nearest-even
    return (unsigned short)(u >> 16);
}
__device__ __forceinline__ float bflo(unsigned u) { return __uint_as_float(u << 16); }
__device__ __forceinline__ float bfhi(unsigned u) { return __uint_as_float(u & 0xffff0000u); }

// =================== bucketed CSR build (bucket = dst>>8; zero global atomics) ===================

// per-block LDS histogram -> counts[bucket][block]
__global__ __launch_bounds__(256) void kb_count(const int* __restrict__ dst, int E, int nb,
                                                int chunk, int* __restrict__ counts) {
    __shared__ int h[512];
    for (int i = threadIdx.x; i < 512; i += 256) h[i] = 0;
    __syncthreads();
    int e0 = blockIdx.x * chunk, e1 = min(e0 + chunk, E);
    for (int e = e0 + threadIdx.x; e < e1; e += 256) atomicAdd(&h[dst[e] >> 8], 1);
    __syncthreads();
    for (int b = threadIdx.x; b < nb; b += 256) counts[b * NBLK + blockIdx.x] = h[b];
}

// per-bucket exclusive scan over blocks (in-place) + total[bucket]
__global__ __launch_bounds__(NBLK) void kb_offsets(int* __restrict__ counts,
                                                   int* __restrict__ total) {
    __shared__ int s[NBLK];
    int b = blockIdx.x, t = threadIdx.x;
    int v = counts[b * NBLK + t];
    s[t] = v; __syncthreads();
    for (int off = 1; off < NBLK; off <<= 1) {
        int x = (t >= off) ? s[t - off] : 0;
        __syncthreads();
        s[t] += x;
        __syncthreads();
    }
    counts[b * NBLK + t] = s[t] - v;          // exclusive
    if (t == NBLK - 1) total[b] = s[t];
}

// exclusive scan of bucket totals -> bbase
__global__ __launch_bounds__(512) void kb_base(const int* __restrict__ total, int nb,
                                               int* __restrict__ bbase) {
    __shared__ int s[512];
    int t = threadIdx.x;
    int v = (t < nb) ? total[t] : 0;
    s[t] = v; __syncthreads();
    for (int off = 1; off < 512; off <<= 1) {
        int x = (t >= off) ? s[t - off] : 0;
        __syncthreads();
        s[t] += x;
        __syncthreads();
    }
    if (t < nb) bbase[t] = s[t] - v;
}

// scatter: LDS cursors seeded from deterministic offsets; LDS atomics only
__global__ __launch_bounds__(NBLK) void kb_scatter(const int* __restrict__ src,
                                                   const int* __restrict__ dst, int E, int nb,
                                                   int chunk,
                                                   const int* __restrict__ counts,
                                                   const int* __restrict__ bbase,
                                                   int2* __restrict__ rec) {
    __shared__ int cur[512];
    int t = threadIdx.x;
    if (t < nb) cur[t] = bbase[t] + counts[t * NBLK + blockIdx.x];
    __syncthreads();
    int e0 = blockIdx.x * chunk, e1 = min(e0 + chunk, E);
    for (int e = e0 + t; e < e1; e += NBLK) {
        int s = src[e], d = dst[e];
        int pos = atomicAdd(&cur[d >> 8], 1);
        rec[pos] = make_int2(s, d);
    }
}

// per-bucket degree count via LDS
__global__ __launch_bounds__(256) void kb_deg(const int2* __restrict__ rec,
                                              const int* __restrict__ bbase,
                                              const int* __restrict__ total,
                                              int* __restrict__ deg, int N) {
    __shared__ int dc[256];
    int b = blockIdx.x, t = threadIdx.x;
    dc[t] = 0; __syncthreads();
    int r0 = bbase[b], r1 = r0 + total[b];
    for (int i = r0 + t; i < r1; i += 256) atomicAdd(&dc[rec[i].y & 255], 1);
    __syncthreads();
    int gn = b * 256 + t;
    if (gn < N) deg[gn] = dc[t];
}

__global__ __launch_bounds__(256) void k_dinv(const int* __restrict__ deg, int N,
                                              float* __restrict__ dinv) {
    int i = blockIdx.x * 256 + threadIdx.x;
    if (i < N) dinv[i] = rsqrtf((float)(deg[i] + 1));
}

// ---------- 3-kernel exclusive scan of PADDED deg -> rowptr ----------
__global__ __launch_bounds__(256) void k_scan_part(const int* __restrict__ deg, int N,
                                                   int* __restrict__ part) {
    int base = blockIdx.x * 1024 + threadIdx.x * 4;
    int s = 0;
#pragma unroll
    for (int i = 0; i < 4; ++i) {
        int idx = base + i;
        if (idx < N) s += (deg[idx] + 7) & ~7;
    }
    __shared__ int red[256];
    red[threadIdx.x] = s; __syncthreads();
    for (int off = 128; off > 0; off >>= 1) {
        if (threadIdx.x < off) red[threadIdx.x] += red[threadIdx.x + off];
        __syncthreads();
    }
    if (threadIdx.x == 0) part[blockIdx.x] = red[0];
}
__global__ void k_scan_mid(int* part, int nb) {
    if (threadIdx.x == 0 && blockIdx.x == 0) {
        int run = 0;
        for (int i = 0; i < nb; ++i) { int t = part[i]; part[i] = run; run += t; }
    }
}
__global__ __launch_bounds__(256) void k_scan_final(const int* __restrict__ deg, int N,
                                                    const int* __restrict__ part,
                                                    int* __restrict__ rowptr) {
    int t = threadIdx.x;
    int base = blockIdx.x * 1024 + t * 4;
    int v[4]; int s = 0;
#pragma unroll
    for (int i = 0; i < 4; ++i) {
        int idx = base + i;
        v[i] = (idx < N) ? ((deg[idx] + 7) & ~7) : 0;
        s += v[i];
    }
    __shared__ int sc[256];
    sc[t] = s; __syncthreads();
    for (int off = 1; off < 256; off <<= 1) {
        int x = (t >= off) ? sc[t - off] : 0;
        __syncthreads();
        sc[t] += x;
        __syncthreads();
    }
    int excl = sc[t] - s + part[blockIdx.x];
#pragma unroll
    for (int i = 0; i < 4; ++i) {
        int idx = base + i;
        if (idx < N) { rowptr[idx] = excl; excl += v[i]; }
    }
}

// per-bucket CSR placement via LDS cursors (csr pre-zeroed; pads stay {0,0})
__global__ __launch_bounds__(256) void kb_place(const int2* __restrict__ rec,
                                                const int* __restrict__ bbase,
                                                const int* __restrict__ total,
                                                const int* __restrict__ rowptr,
                                                const float* __restrict__ dinv,
                                                int2* __restrict__ csr, int N) {
    __shared__ int cur[256];
    int b = blockIdx.x, t = threadIdx.x;
    int gn = b * 256 + t;
    cur[t] = (gn < N) ? rowptr[gn] : 0;
    __syncthreads();
    int r0 = bbase[b], r1 = r0 + total[b];
    for (int i = r0 + t; i < r1; i += 256) {
        int2 rc = rec[i];
        int pos = atomicAdd(&cur[rc.y & 255], 1);
        float w = dinv[rc.x] * dinv[rc.y];
        csr[pos] = make_int2(rc.x, __float_as_int(w));
    }
}

// =================== W prep: bf16 A-fragment layout ===================
__global__ __launch_bounds__(256) void k_wprep(const float* __restrict__ W,
                                               unsigned short* __restrict__ Wt) {
    int t = blockIdx.x * 256 + threadIdx.x;   // 2048 = 32 frags * 64 lanes
    if (t >= 2048) return;
    int f = t >> 6, lane = t & 63;
    int kc = f >> 3, nt = f & 7;
    int kbase = kc * 32 + (lane >> 4) * 8;
    int n = nt * 16 + (lane & 15);
    unsigned short t8[8];
#pragma unroll
    for (int j = 0; j < 8; ++j) t8[j] = f2bf(W[(size_t)(kbase + j) * 128 + n]);
    unsigned short* o = &Wt[(size_t)t * 8];
    *(ushort4*)&o[0] = *(ushort4*)&t8[0];
    *(ushort4*)&o[4] = *(ushort4*)&t8[4];
}

// =================== MFMA GEMM: Hout(bf16) = act(X) @ W ===================
__global__ __launch_bounds__(256) void k_gemm(const void* __restrict__ Xv,
                                              const unsigned short* __restrict__ Wt,
                                              const float* __restrict__ scale,
                                              const float* __restrict__ shift,
                                              unsigned short* __restrict__ Hout,
                                              int N, int xbf16) {
    __shared__ unsigned short sX[64 * 136];
    const int tid = threadIdx.x;
    const int rowBase = blockIdx.x * 64;

    if (!xbf16) {
        const float* X = (const float*)Xv;
#pragma unroll
        for (int i = 0; i < 8; ++i) {
            int f4 = tid + 256 * i;
            int r = f4 >> 5; int k4 = (f4 & 31) * 4;
            int gr = rowBase + r;
            float4 v = make_float4(0.f, 0.f, 0.f, 0.f);
            if (gr < N) v = *(const float4*)&X[(size_t)gr * 128 + k4];
            ushort4 p;
            p.x = f2bf(v.x); p.y = f2bf(v.y); p.z = f2bf(v.z); p.w = f2bf(v.w);
            *(ushort4*)&sX[r * 136 + k4] = p;
        }
    } else {
        const int4* X = (const int4*)Xv;
#pragma unroll
        for (int i = 0; i < 4; ++i) {
            int f8 = tid + 256 * i;
            int r = f8 >> 4; int k8 = (f8 & 15) * 8;
            int gr = rowBase + r;
            int4 u = make_int4(0, 0, 0, 0);
            if (gr < N) u = X[(size_t)gr * 16 + (f8 & 15)];
            float fv[8] = { bflo(u.x), bfhi(u.x), bflo(u.y), bfhi(u.y),
                            bflo(u.z), bfhi(u.z), bflo(u.w), bfhi(u.w) };
            unsigned short t8[8];
#pragma unroll
            for (int j = 0; j < 8; ++j)
                t8[j] = f2bf(fmaxf(fmaf(fv[j], scale[k8 + j], shift[k8 + j]), 0.f));
            *(ushort4*)&sX[r * 136 + k8]     = *(ushort4*)&t8[0];
            *(ushort4*)&sX[r * 136 + k8 + 4] = *(ushort4*)&t8[4];
        }
    }
    __syncthreads();

    const int lane = tid & 63, wave = tid >> 6;
    const int m = lane & 15, q = lane >> 4;
    const int rowOff = (wave * 16 + m) * 136 + q * 8;
    f32x4 acc[8];
#pragma unroll
    for (int nt = 0; nt < 8; ++nt) acc[nt] = (f32x4){0.f, 0.f, 0.f, 0.f};
    const bf16x8* WtF = (const bf16x8*)Wt;
#pragma unroll
    for (int kc = 0; kc < 4; ++kc) {
        bf16x8 xb = *(const bf16x8*)&sX[rowOff + kc * 32];
#pragma unroll
        for (int nt = 0; nt < 8; ++nt) {
            bf16x8 wa = WtF[(kc * 8 + nt) * 64 + lane];
            acc[nt] = __builtin_amdgcn_mfma_f32_16x16x32_bf16(wa, xb, acc[nt], 0, 0, 0);
        }
    }
    int grow = rowBase + wave * 16 + m;
    if (grow < N) {
#pragma unroll
        for (int nt = 0; nt < 8; ++nt) {
            ushort4 p;
            p.x = f2bf(acc[nt][0]); p.y = f2bf(acc[nt][1]);
            p.z = f2bf(acc[nt][2]); p.w = f2bf(acc[nt][3]);
            *(ushort4*)&Hout[(size_t)grow * 128 + nt * 16 + q * 4] = p;
        }
    }
}

// =================== aggregation: pad-to-8, clamp-free, bf16 in / bf16 out ===================
__global__ __launch_bounds__(256) void k_agg(const unsigned short* __restrict__ H,
                                             const int* __restrict__ rowptr,
                                             const int* __restrict__ deg,
                                             const int2* __restrict__ csr,
                                             const float* __restrict__ dinv,
                                             const float* __restrict__ bias,
                                             unsigned* __restrict__ out, int N) {
    int wave = threadIdx.x >> 6;
    int lane = threadIdx.x & 63;
    int node = blockIdx.x * 4 + wave;
    if (node >= N) return;
    const unsigned* Hu = (const unsigned*)H;
    int start = rowptr[node];
    int pd = (deg[node] + 7) & ~7;
    float a0 = 0.f, a1 = 0.f;
    const int4* cp = (const int4*)(csr + start);
    for (int j = 0; j < pd; j += 8) {
        int4 q0 = cp[0], q1 = cp[1], q2 = cp[2], q3 = cp[3];
        cp += 4;
        unsigned u0 = Hu[(size_t)q0.x * 64 + lane];
        unsigned u1 = Hu[(size_t)q0.z * 64 + lane];
        unsigned u2 = Hu[(size_t)q1.x * 64 + lane];
        unsigned u3 = Hu[(size_t)q1.z * 64 + lane];
        unsigned u4 = Hu[(size_t)q2.x * 64 + lane];
        unsigned u5 = Hu[(size_t)q2.z * 64 + lane];
        unsigned u6 = Hu[(size_t)q3.x * 64 + lane];
        unsigned u7 = Hu[(size_t)q3.z * 64 + lane];
        float w0 = __int_as_float(q0.y), w1 = __int_as_float(q0.w);
        float w2 = __int_as_float(q1.y), w3 = __int_as_float(q1.w);
        float w4 = __int_as_float(q2.y), w5 = __int_as_float(q2.w);
        float w6 = __int_as_float(q3.y), w7 = __int_as_float(q3.w);
        a0 = fmaf(w0, bflo(u0), a0); a1 = fmaf(w0, bfhi(u0), a1);
        a0 = fmaf(w1, bflo(u1), a0); a1 = fmaf(w1, bfhi(u1), a1);
        a0 = fmaf(w2, bflo(u2), a0); a1 = fmaf(w2, bfhi(u2), a1);
        a0 = fmaf(w3, bflo(u3), a0); a1 = fmaf(w3, bfhi(u3), a1);
        a0 = fmaf(w4, bflo(u4), a0); a1 = fmaf(w4, bfhi(u4), a1);
        a0 = fmaf(w5, bflo(u5), a0); a1 = fmaf(w5, bfhi(u5), a1);
        a0 = fmaf(w6, bflo(u6), a0); a1 = fmaf(w6, bfhi(u6), a1);
        a0 = fmaf(w7, bflo(u7), a0); a1 = fmaf(w7, bfhi(u7), a1);
    }
    { // self loop
        float dn = dinv[node];
        float w = dn * dn;
        unsigned u = Hu[(size_t)node * 64 + lane];
        a0 = fmaf(w, bflo(u), a0);
        a1 = fmaf(w, bfhi(u), a1);
    }
    float2 bv = ((const float2*)bias)[lane];
    a0 += bv.x; a1 += bv.y;
    out[(size_t)node * 64 + lane] = (unsigned)f2bf(a0) | ((unsigned)f2bf(a1) << 16);
}

// ---------- BN column stats over bf16 buffer ----------
__global__ __launch_bounds__(256) void k_stats(const unsigned* __restrict__ Bu, int N,
                                               float* __restrict__ S1,
                                               float* __restrict__ S2) {
    int c2 = threadIdx.x & 63;
    int rh = threadIdx.x >> 6;
    float s1a = 0.f, s2a = 0.f, s1b = 0.f, s2b = 0.f;
    for (int r = blockIdx.x * 4 + rh; r < N; r += gridDim.x * 4) {
        unsigned u = Bu[(size_t)r * 64 + c2];
        float va = bflo(u), vb = bfhi(u);
        s1a += va; s2a = fmaf(va, va, s2a);
        s1b += vb; s2b = fmaf(vb, vb, s2b);
    }
    atomicAdd(&S1[2 * c2], s1a); atomicAdd(&S2[2 * c2], s2a);
    atomicAdd(&S1[2 * c2 + 1], s1b); atomicAdd(&S2[2 * c2 + 1], s2b);
}

__global__ void k_bnfinal(const float* __restrict__ S1, const float* __restrict__ S2,
                          const float* __restrict__ g, const float* __restrict__ be,
                          float* __restrict__ scale, float* __restrict__ shift,
                          float invN) {
    int c = threadIdx.x;
    if (c >= 128) return;
    float mu = S1[c] * invN;
    float var = S2[c] * invN - mu * mu;
    float sc = g[c] * rsqrtf(var + 1e-5f);
    scale[c] = sc;
    shift[c] = fmaf(-mu, sc, be[c]);
}

// ---------- per-graph histogram of batch ----------
__global__ __launch_bounds__(256) void k_hist(const int* __restrict__ batch, int N,
                                              int* __restrict__ gcnt) {
    __shared__ int h[64];
    if (threadIdx.x < 64) h[threadIdx.x] = 0;
    __syncthreads();
    for (int i = blockIdx.x * 256 + threadIdx.x; i < N; i += gridDim.x * 256)
        atomicAdd(&h[batch[i]], 1);
    __syncthreads();
    if (threadIdx.x < 64 && h[threadIdx.x]) atomicAdd(&gcnt[threadIdx.x], h[threadIdx.x]);
}

// ---------- pool ----------
__global__ __launch_bounds__(256) void k_pool(const unsigned* __restrict__ Bu,
                                              const float* __restrict__ scale,
                                              const float* __restrict__ shift,
                                              const int* __restrict__ batch, int N,
                                              int rpb, float* __restrict__ pooled) {
    int c2 = threadIdx.x & 63;
    int rh = threadIdx.x >> 6;
    int r0 = blockIdx.x * rpb;
    int r1 = min(r0 + rpb, N);
    float sca = scale[2 * c2], sha = shift[2 * c2];
    float scb = scale[2 * c2 + 1], shb = shift[2 * c2 + 1];
    float aa = 0.f, ab = 0.f; int cur = -1;
    for (int r = r0 + rh; r < r1; r += 4) {
        int g = batch[r];
        if (g != cur) {
            if (cur >= 0) {
                atomicAdd(&pooled[cur * 128 + 2 * c2], aa);
                atomicAdd(&pooled[cur * 128 + 2 * c2 + 1], ab);
            }
            aa = ab = 0.f; cur = g;
        }
        unsigned u = Bu[(size_t)r * 64 + c2];
        aa += fmaxf(fmaf(bflo(u), sca, sha), 0.f);
        ab += fmaxf(fmaf(bfhi(u), scb, shb), 0.f);
    }
    if (cur >= 0) {
        atomicAdd(&pooled[cur * 128 + 2 * c2], aa);
        atomicAdd(&pooled[cur * 128 + 2 * c2 + 1], ab);
    }
}

// ---------- FC ----------
__global__ __launch_bounds__(256) void k_fc(const float* __restrict__ pooled,
                                            const int* __restrict__ gcnt,
                                            const float* __restrict__ Wfc,
                                            const float* __restrict__ bfc,
                                            float* __restrict__ out) {
    int idx = blockIdx.x * 256 + threadIdx.x;
    if (idx >= 64 * 32) return;
    int g = idx >> 5, o = idx & 31;
    float inv = 1.f / fmaxf((float)gcnt[g], 1.f);
    float acc = bfc[o];
    for (int k = 0; k < 128; ++k)
        acc = fmaf(pooled[g * 128 + k] * inv, Wfc[k * 32 + o], acc);
    out[idx] = acc;
}

extern "C" void kernel_launch(void* const* d_in, const int* in_sizes, int n_in,
                              void* d_out, int out_size, void* d_ws, size_t ws_size,
                              hipStream_t stream) {
    const float* x    = (const float*)d_in[0];
    const int*  eidx  = (const int*)d_in[1];
    const int*  batch = (const int*)d_in[2];
    const float* W0 = (const float*)d_in[3];
    const float* b0 = (const float*)d_in[4];
    const float* g0 = (const float*)d_in[5];
    const float* be0 = (const float*)d_in[6];
    const float* W1 = (const float*)d_in[7];
    const float* b1 = (const float*)d_in[8];
    const float* g1 = (const float*)d_in[9];
    const float* be1 = (const float*)d_in[10];
    const float* Wfc = (const float*)d_in[11];
    const float* bfc = (const float*)d_in[12];
    float* out = (float*)d_out;

    const int N = in_sizes[0] / 128;
    const int E = in_sizes[1] / 2;
    const int* esrc = eidx;
    const int* edst = eidx + E;
    const int NB = (N + 255) >> 8;               // buckets of 256 nodes (<=512)
    const size_t paddedE = (size_t)E + 7 * (size_t)N;

    // ---- workspace carve-up ----
    char* base = (char*)d_ws;
    size_t off = 0;
    auto take = [&](size_t bytes) -> char* {
        char* p = base + off;
        off = (off + bytes + 255) & ~(size_t)255;
        return p;
    };
    unsigned short* hA = (unsigned short*)take((size_t)N * 128 * 2); // bf16 h; aliased as rec
    int2* rec = (int2*)hA;                                           // bucket records (dead before gemm1)
    unsigned* B = (unsigned*)take((size_t)N * 64 * 4);               // bf16-packed agg buffer
    int2* csr   = (int2*)take(paddedE * 8);
    int* rowptr = (int*)take((size_t)N * 4);
    int* deg    = (int*)take((size_t)N * 4);
    float* dinv = (float*)take((size_t)N * 4);
    int* counts = (int*)take((size_t)512 * NBLK * 4);                // 1 MB
    int* total  = (int*)take(512 * 4);
    int* bbase  = (int*)take(512 * 4);
    int* part   = (int*)take(1024 * 4);
    unsigned short* W0t = (unsigned short*)take(16384 * 2);
    unsigned short* W1t = (unsigned short*)take(16384 * 2);
    char* zeroB0 = base + off;
    float* S1a = (float*)take(128 * 4);
    float* S2a = (float*)take(128 * 4);
    float* S1b = (float*)take(128 * 4);
    float* S2b = (float*)take(128 * 4);
    float* pooled = (float*)take(64 * 128 * 4);
    int*   gcnt   = (int*)take(64 * 4);
    size_t zeroB_bytes = (size_t)((base + off) - zeroB0);
    float* scale1 = (float*)take(128 * 4);
    float* shift1 = (float*)take(128 * 4);
    float* scale2 = (float*)take(128 * 4);
    float* shift2 = (float*)take(128 * 4);
    (void)ws_size; (void)n_in; (void)out_size;

    hipMemsetAsync(zeroB0, 0, zeroB_bytes, stream);
    hipMemsetAsync(csr, 0, paddedE * 8, stream);   // pad entries -> {src=0, w=0}

    // weight prep (tiny)
    k_wprep<<<8, 256, 0, stream>>>(W0, W0t);
    k_wprep<<<8, 256, 0, stream>>>(W1, W1t);

    // ---- bucketed CSR build (deterministic, no global atomics) ----
    const int CH256 = (E + NBLK - 1) / NBLK;
    kb_count<<<NBLK, 256, 0, stream>>>(edst, E, NB, CH256, counts);
    kb_offsets<<<NB, NBLK, 0, stream>>>(counts, total);
    kb_base<<<1, 512, 0, stream>>>(total, NB, bbase);
    kb_scatter<<<NBLK, NBLK, 0, stream>>>(esrc, edst, E, NB, CH256, counts, bbase, rec);
    kb_deg<<<NB, 256, 0, stream>>>(rec, bbase, total, deg, N);
    k_dinv<<<(N + 255) / 256, 256, 0, stream>>>(deg, N, dinv);
    const int nbScan = (N + 1023) / 1024;
    k_scan_part<<<nbScan, 256, 0, stream>>>(deg, N, part);
    k_scan_mid<<<1, 64, 0, stream>>>(part, nbScan);
    k_scan_final<<<nbScan, 256, 0, stream>>>(deg, N, part, rowptr);
    kb_place<<<NB, 256, 0, stream>>>(rec, bbase, total, rowptr, dinv, csr, N);

    const int gGemm = (N + 63) / 64;
    const int gAgg  = (N + 3) / 4;
    const float invN = 1.0f / (float)N;

    // layer 1
    k_gemm<<<gGemm, 256, 0, stream>>>(x, W0t, scale1, shift1, hA, N, 0);
    k_agg<<<gAgg, 256, 0, stream>>>(hA, rowptr, deg, csr, dinv, b0, B, N);
    k_stats<<<256, 256, 0, stream>>>(B, N, S1a, S2a);
    k_bnfinal<<<1, 128, 0, stream>>>(S1a, S2a, g0, be0, scale1, shift1, invN);

    // layer 2 (BN1+ReLU fused into GEMM2's staging)
    k_gemm<<<gGemm, 256, 0, stream>>>(B, W1t, scale1, shift1, hA, N, 1);
    k_agg<<<gAgg, 256, 0, stream>>>(hA, rowptr, deg, csr, dinv, b1, B, N);
    k_stats<<<256, 256, 0, stream>>>(B, N, S1b, S2b);
    k_bnfinal<<<1, 128, 0, stream>>>(S1b, S2b, g1, be1, scale2, shift2, invN);

    // pool (BN2+ReLU fused) + FC
    k_hist<<<256, 256, 0, stream>>>(batch, N, gcnt);
    const int rpb = (N + 511) / 512;
    k_pool<<<(N + rpb - 1) / rpb, 256, 0, stream>>>(B, scale2, shift2, batch, N, rpb, pooled);
    k_fc<<<8, 256, 0, stream>>>(pooled, gcnt, Wfc, bfc, out);
}

// Round 5
// 464.317 us; speedup vs baseline: 2.3569x; 1.1773x over previous
//
#include <hip/hip_runtime.h>

typedef short bf16x8 __attribute__((ext_vector_type(8)));
typedef float f32x4 __attribute__((ext_vector_type(4)));

#define NBLK 512   // scatter blocks (fixed for deterministic two-level offsets)
#define NSTAT 512  // stats partial blocks

// ---------- bf16 helpers ----------
__device__ __forceinline__ unsigned short f2bf(float f) {
    unsigned u = __float_as_uint(f);
    u += 0x7fffu + ((u >> 16) & 1u);   // round-to-nearest-even
    return (unsigned short)(u >> 16);
}
__device__ __forceinline__ float bflo(unsigned u) { return __uint_as_float(u << 16); }
__device__ __forceinline__ float bfhi(unsigned u) { return __uint_as_float(u & 0xffff0000u); }

// =================== bucketed CSR build (bucket = dst>>8; zero global atomics) ===================

__global__ __launch_bounds__(256) void kb_count(const int* __restrict__ dst, int E, int nb,
                                                int chunk, int* __restrict__ counts) {
    __shared__ int h[512];
    for (int i = threadIdx.x; i < 512; i += 256) h[i] = 0;
    __syncthreads();
    int e0 = blockIdx.x * chunk, e1 = min(e0 + chunk, E);
    for (int e = e0 + threadIdx.x; e < e1; e += 256) atomicAdd(&h[dst[e] >> 8], 1);
    __syncthreads();
    for (int b = threadIdx.x; b < nb; b += 256) counts[b * NBLK + blockIdx.x] = h[b];
}

__global__ __launch_bounds__(NBLK) void kb_offsets(int* __restrict__ counts,
                                                   int* __restrict__ total) {
    __shared__ int s[NBLK];
    int b = blockIdx.x, t = threadIdx.x;
    int v = counts[b * NBLK + t];
    s[t] = v; __syncthreads();
    for (int off = 1; off < NBLK; off <<= 1) {
        int x = (t >= off) ? s[t - off] : 0;
        __syncthreads();
        s[t] += x;
        __syncthreads();
    }
    counts[b * NBLK + t] = s[t] - v;          // exclusive
    if (t == NBLK - 1) total[b] = s[t];
}

__global__ __launch_bounds__(512) void kb_base(const int* __restrict__ total, int nb,
                                               int* __restrict__ bbase) {
    __shared__ int s[512];
    int t = threadIdx.x;
    int v = (t < nb) ? total[t] : 0;
    s[t] = v; __syncthreads();
    for (int off = 1; off < 512; off <<= 1) {
        int x = (t >= off) ? s[t - off] : 0;
        __syncthreads();
        s[t] += x;
        __syncthreads();
    }
    if (t < nb) bbase[t] = s[t] - v;
}

__global__ __launch_bounds__(NBLK) void kb_scatter(const int* __restrict__ src,
                                                   const int* __restrict__ dst, int E, int nb,
                                                   int chunk,
                                                   const int* __restrict__ counts,
                                                   const int* __restrict__ bbase,
                                                   int2* __restrict__ rec) {
    __shared__ int cur[512];
    int t = threadIdx.x;
    if (t < nb) cur[t] = bbase[t] + counts[t * NBLK + blockIdx.x];
    __syncthreads();
    int e0 = blockIdx.x * chunk, e1 = min(e0 + chunk, E);
    for (int e = e0 + t; e < e1; e += NBLK) {
        int s = src[e], d = dst[e];
        int pos = atomicAdd(&cur[d >> 8], 1);
        rec[pos] = make_int2(s, d);
    }
}

__global__ __launch_bounds__(256) void kb_deg(const int2* __restrict__ rec,
                                              const int* __restrict__ bbase,
                                              const int* __restrict__ total,
                                              int* __restrict__ deg, int N) {
    __shared__ int dc[256];
    int b = blockIdx.x, t = threadIdx.x;
    dc[t] = 0; __syncthreads();
    int r0 = bbase[b], r1 = r0 + total[b];
    for (int i = r0 + t; i < r1; i += 256) atomicAdd(&dc[rec[i].y & 255], 1);
    __syncthreads();
    int gn = b * 256 + t;
    if (gn < N) deg[gn] = dc[t];
}

__global__ __launch_bounds__(256) void k_dinv(const int* __restrict__ deg, int N,
                                              float* __restrict__ dinv) {
    int i = blockIdx.x * 256 + threadIdx.x;
    if (i < N) dinv[i] = rsqrtf((float)(deg[i] + 1));
}

// ---------- 3-kernel exclusive scan of PADDED deg -> rowptr ----------
__global__ __launch_bounds__(256) void k_scan_part(const int* __restrict__ deg, int N,
                                                   int* __restrict__ part) {
    int base = blockIdx.x * 1024 + threadIdx.x * 4;
    int s = 0;
#pragma unroll
    for (int i = 0; i < 4; ++i) {
        int idx = base + i;
        if (idx < N) s += (deg[idx] + 7) & ~7;
    }
    __shared__ int red[256];
    red[threadIdx.x] = s; __syncthreads();
    for (int off = 128; off > 0; off >>= 1) {
        if (threadIdx.x < off) red[threadIdx.x] += red[threadIdx.x + off];
        __syncthreads();
    }
    if (threadIdx.x == 0) part[blockIdx.x] = red[0];
}
__global__ void k_scan_mid(int* part, int nb) {
    if (threadIdx.x == 0 && blockIdx.x == 0) {
        int run = 0;
        for (int i = 0; i < nb; ++i) { int t = part[i]; part[i] = run; run += t; }
    }
}
__global__ __launch_bounds__(256) void k_scan_final(const int* __restrict__ deg, int N,
                                                    const int* __restrict__ part,
                                                    int* __restrict__ rowptr) {
    int t = threadIdx.x;
    int base = blockIdx.x * 1024 + t * 4;
    int v[4]; int s = 0;
#pragma unroll
    for (int i = 0; i < 4; ++i) {
        int idx = base + i;
        v[i] = (idx < N) ? ((deg[idx] + 7) & ~7) : 0;
        s += v[i];
    }
    __shared__ int sc[256];
    sc[t] = s; __syncthreads();
    for (int off = 1; off < 256; off <<= 1) {
        int x = (t >= off) ? sc[t - off] : 0;
        __syncthreads();
        sc[t] += x;
        __syncthreads();
    }
    int excl = sc[t] - s + part[blockIdx.x];
#pragma unroll
    for (int i = 0; i < 4; ++i) {
        int idx = base + i;
        if (idx < N) { rowptr[idx] = excl; excl += v[i]; }
    }
}

__global__ __launch_bounds__(256) void kb_place(const int2* __restrict__ rec,
                                                const int* __restrict__ bbase,
                                                const int* __restrict__ total,
                                                const int* __restrict__ rowptr,
                                                const float* __restrict__ dinv,
                                                int2* __restrict__ csr, int N) {
    __shared__ int cur[256];
    int b = blockIdx.x, t = threadIdx.x;
    int gn = b * 256 + t;
    cur[t] = (gn < N) ? rowptr[gn] : 0;
    __syncthreads();
    int r0 = bbase[b], r1 = r0 + total[b];
    for (int i = r0 + t; i < r1; i += 256) {
        int2 rc = rec[i];
        int pos = atomicAdd(&cur[rc.y & 255], 1);
        float w = dinv[rc.x] * dinv[rc.y];
        csr[pos] = make_int2(rc.x, __float_as_int(w));
    }
}

// =================== W prep: bf16 A-fragment layout ===================
__global__ __launch_bounds__(256) void k_wprep(const float* __restrict__ W,
                                               unsigned short* __restrict__ Wt) {
    int t = blockIdx.x * 256 + threadIdx.x;   // 2048 = 32 frags * 64 lanes
    if (t >= 2048) return;
    int f = t >> 6, lane = t & 63;
    int kc = f >> 3, nt = f & 7;
    int kbase = kc * 32 + (lane >> 4) * 8;
    int n = nt * 16 + (lane & 15);
    unsigned short t8[8];
#pragma unroll
    for (int j = 0; j < 8; ++j) t8[j] = f2bf(W[(size_t)(kbase + j) * 128 + n]);
    unsigned short* o = &Wt[(size_t)t * 8];
    *(ushort4*)&o[0] = *(ushort4*)&t8[0];
    *(ushort4*)&o[4] = *(ushort4*)&t8[4];
}

// =================== MFMA GEMM: Hout(bf16) = act(X) @ W ===================
__global__ __launch_bounds__(256) void k_gemm(const void* __restrict__ Xv,
                                              const unsigned short* __restrict__ Wt,
                                              const float* __restrict__ scale,
                                              const float* __restrict__ shift,
                                              unsigned short* __restrict__ Hout,
                                              int N, int xbf16) {
    __shared__ unsigned short sX[64 * 136];
    const int tid = threadIdx.x;
    const int rowBase = blockIdx.x * 64;

    if (!xbf16) {
        const float* X = (const float*)Xv;
#pragma unroll
        for (int i = 0; i < 8; ++i) {
            int f4 = tid + 256 * i;
            int r = f4 >> 5; int k4 = (f4 & 31) * 4;
            int gr = rowBase + r;
            float4 v = make_float4(0.f, 0.f, 0.f, 0.f);
            if (gr < N) v = *(const float4*)&X[(size_t)gr * 128 + k4];
            ushort4 p;
            p.x = f2bf(v.x); p.y = f2bf(v.y); p.z = f2bf(v.z); p.w = f2bf(v.w);
            *(ushort4*)&sX[r * 136 + k4] = p;
        }
    } else {
        const int4* X = (const int4*)Xv;
#pragma unroll
        for (int i = 0; i < 4; ++i) {
            int f8 = tid + 256 * i;
            int r = f8 >> 4; int k8 = (f8 & 15) * 8;
            int gr = rowBase + r;
            int4 u = make_int4(0, 0, 0, 0);
            if (gr < N) u = X[(size_t)gr * 16 + (f8 & 15)];
            float fv[8] = { bflo(u.x), bfhi(u.x), bflo(u.y), bfhi(u.y),
                            bflo(u.z), bfhi(u.z), bflo(u.w), bfhi(u.w) };
            unsigned short t8[8];
#pragma unroll
            for (int j = 0; j < 8; ++j)
                t8[j] = f2bf(fmaxf(fmaf(fv[j], scale[k8 + j], shift[k8 + j]), 0.f));
            *(ushort4*)&sX[r * 136 + k8]     = *(ushort4*)&t8[0];
            *(ushort4*)&sX[r * 136 + k8 + 4] = *(ushort4*)&t8[4];
        }
    }
    __syncthreads();

    const int lane = tid & 63, wave = tid >> 6;
    const int m = lane & 15, q = lane >> 4;
    const int rowOff = (wave * 16 + m) * 136 + q * 8;
    f32x4 acc[8];
#pragma unroll
    for (int nt = 0; nt < 8; ++nt) acc[nt] = (f32x4){0.f, 0.f, 0.f, 0.f};
    const bf16x8* WtF = (const bf16x8*)Wt;
#pragma unroll
    for (int kc = 0; kc < 4; ++kc) {
        bf16x8 xb = *(const bf16x8*)&sX[rowOff + kc * 32];
#pragma unroll
        for (int nt = 0; nt < 8; ++nt) {
            bf16x8 wa = WtF[(kc * 8 + nt) * 64 + lane];
            acc[nt] = __builtin_amdgcn_mfma_f32_16x16x32_bf16(wa, xb, acc[nt], 0, 0, 0);
        }
    }
    int grow = rowBase + wave * 16 + m;
    if (grow < N) {
#pragma unroll
        for (int nt = 0; nt < 8; ++nt) {
            ushort4 p;
            p.x = f2bf(acc[nt][0]); p.y = f2bf(acc[nt][1]);
            p.z = f2bf(acc[nt][2]); p.w = f2bf(acc[nt][3]);
            *(ushort4*)&Hout[(size_t)grow * 128 + nt * 16 + q * 4] = p;
        }
    }
}

// =================== aggregation: pad-to-8, clamp-free, bf16 in / bf16 out ===================
__global__ __launch_bounds__(256) void k_agg(const unsigned short* __restrict__ H,
                                             const int* __restrict__ rowptr,
                                             const int* __restrict__ deg,
                                             const int2* __restrict__ csr,
                                             const float* __restrict__ dinv,
                                             const float* __restrict__ bias,
                                             unsigned* __restrict__ out, int N) {
    int wave = threadIdx.x >> 6;
    int lane = threadIdx.x & 63;
    int node = blockIdx.x * 4 + wave;
    if (node >= N) return;
    const unsigned* Hu = (const unsigned*)H;
    int start = rowptr[node];
    int pd = (deg[node] + 7) & ~7;
    float a0 = 0.f, a1 = 0.f;
    const int4* cp = (const int4*)(csr + start);
    for (int j = 0; j < pd; j += 8) {
        int4 q0 = cp[0], q1 = cp[1], q2 = cp[2], q3 = cp[3];
        cp += 4;
        unsigned u0 = Hu[(size_t)q0.x * 64 + lane];
        unsigned u1 = Hu[(size_t)q0.z * 64 + lane];
        unsigned u2 = Hu[(size_t)q1.x * 64 + lane];
        unsigned u3 = Hu[(size_t)q1.z * 64 + lane];
        unsigned u4 = Hu[(size_t)q2.x * 64 + lane];
        unsigned u5 = Hu[(size_t)q2.z * 64 + lane];
        unsigned u6 = Hu[(size_t)q3.x * 64 + lane];
        unsigned u7 = Hu[(size_t)q3.z * 64 + lane];
        float w0 = __int_as_float(q0.y), w1 = __int_as_float(q0.w);
        float w2 = __int_as_float(q1.y), w3 = __int_as_float(q1.w);
        float w4 = __int_as_float(q2.y), w5 = __int_as_float(q2.w);
        float w6 = __int_as_float(q3.y), w7 = __int_as_float(q3.w);
        a0 = fmaf(w0, bflo(u0), a0); a1 = fmaf(w0, bfhi(u0), a1);
        a0 = fmaf(w1, bflo(u1), a0); a1 = fmaf(w1, bfhi(u1), a1);
        a0 = fmaf(w2, bflo(u2), a0); a1 = fmaf(w2, bfhi(u2), a1);
        a0 = fmaf(w3, bflo(u3), a0); a1 = fmaf(w3, bfhi(u3), a1);
        a0 = fmaf(w4, bflo(u4), a0); a1 = fmaf(w4, bfhi(u4), a1);
        a0 = fmaf(w5, bflo(u5), a0); a1 = fmaf(w5, bfhi(u5), a1);
        a0 = fmaf(w6, bflo(u6), a0); a1 = fmaf(w6, bfhi(u6), a1);
        a0 = fmaf(w7, bflo(u7), a0); a1 = fmaf(w7, bfhi(u7), a1);
    }
    { // self loop
        float dn = dinv[node];
        float w = dn * dn;
        unsigned u = Hu[(size_t)node * 64 + lane];
        a0 = fmaf(w, bflo(u), a0);
        a1 = fmaf(w, bfhi(u), a1);
    }
    float2 bv = ((const float2*)bias)[lane];
    a0 += bv.x; a1 += bv.y;
    out[(size_t)node * 64 + lane] = (unsigned)f2bf(a0) | ((unsigned)f2bf(a1) << 16);
}

// ---------- BN column stats: int4 loads, shuffle-reduce, per-block partials ----------
__global__ __launch_bounds__(256) void k_stats(const int4* __restrict__ B4, int N,
                                               float* __restrict__ P1,
                                               float* __restrict__ P2) {
    int tid = threadIdx.x;
    int lane = tid & 63, wave = tid >> 6;
    int c = lane & 15;          // int4 column -> features 8c..8c+7
    int rsub = lane >> 4;       // 4 rows per wave per iteration
    float s1[8] = {0.f,0.f,0.f,0.f,0.f,0.f,0.f,0.f};
    float s2[8] = {0.f,0.f,0.f,0.f,0.f,0.f,0.f,0.f};
    for (int r = blockIdx.x * 16 + wave * 4 + rsub; r < N; r += NSTAT * 16) {
        int4 u = B4[(size_t)r * 16 + c];
        float f[8] = { bflo(u.x), bfhi(u.x), bflo(u.y), bfhi(u.y),
                       bflo(u.z), bfhi(u.z), bflo(u.w), bfhi(u.w) };
#pragma unroll
        for (int j = 0; j < 8; ++j) { s1[j] += f[j]; s2[j] = fmaf(f[j], f[j], s2[j]); }
    }
#pragma unroll
    for (int j = 0; j < 8; ++j) {
        s1[j] += __shfl_xor(s1[j], 16, 64);
        s1[j] += __shfl_xor(s1[j], 32, 64);
        s2[j] += __shfl_xor(s2[j], 16, 64);
        s2[j] += __shfl_xor(s2[j], 32, 64);
    }
    __shared__ float ls1[4][128], ls2[4][128];
    if (rsub == 0) {
#pragma unroll
        for (int j = 0; j < 8; ++j) { ls1[wave][c * 8 + j] = s1[j]; ls2[wave][c * 8 + j] = s2[j]; }
    }
    __syncthreads();
    if (tid < 128) {
        P1[blockIdx.x * 128 + tid] = ls1[0][tid] + ls1[1][tid] + ls1[2][tid] + ls1[3][tid];
        P2[blockIdx.x * 128 + tid] = ls2[0][tid] + ls2[1][tid] + ls2[2][tid] + ls2[3][tid];
    }
}

// ---------- reduce partials + finalize BN scale/shift ----------
__global__ __launch_bounds__(256) void k_bnfinal(const float* __restrict__ P1,
                          const float* __restrict__ P2,
                          const float* __restrict__ g, const float* __restrict__ be,
                          float* __restrict__ scale, float* __restrict__ shift,
                          float invN) {
    __shared__ float sm[256];
    int t = threadIdx.x;
    int c = t & 127;
    const float* P = (t < 128) ? P1 : P2;
    float s = 0.f;
    for (int b = 0; b < NSTAT; ++b) s += P[b * 128 + c];
    sm[t] = s;
    __syncthreads();
    if (t < 128) {
        float mu = sm[t] * invN;
        float var = sm[t + 128] * invN - mu * mu;
        float sc = g[t] * rsqrtf(var + 1e-5f);
        scale[t] = sc;
        shift[t] = fmaf(-mu, sc, be[t]);
    }
}

// ---------- per-graph histogram of batch ----------
__global__ __launch_bounds__(256) void k_hist(const int* __restrict__ batch, int N,
                                              int* __restrict__ gcnt) {
    __shared__ int h[64];
    if (threadIdx.x < 64) h[threadIdx.x] = 0;
    __syncthreads();
    for (int i = blockIdx.x * 256 + threadIdx.x; i < N; i += gridDim.x * 256)
        atomicAdd(&h[batch[i]], 1);
    __syncthreads();
    if (threadIdx.x < 64 && h[threadIdx.x]) atomicAdd(&gcnt[threadIdx.x], h[threadIdx.x]);
}

// ---------- pool: int4 loads, 16 row-walkers x 8 features ----------
__global__ __launch_bounds__(256) void k_pool(const int4* __restrict__ B4,
                                              const float* __restrict__ scale,
                                              const float* __restrict__ shift,
                                              const int* __restrict__ batch, int N,
                                              int rpb, float* __restrict__ pooled) {
    int tid = threadIdx.x;
    int c = tid & 15;       // features 8c..8c+7
    int rh = tid >> 4;      // 16 walkers
    int r0 = blockIdx.x * rpb;
    int r1 = min(r0 + rpb, N);
    float sc[8], sh[8];
#pragma unroll
    for (int j = 0; j < 8; ++j) { sc[j] = scale[c * 8 + j]; sh[j] = shift[c * 8 + j]; }
    float acc[8] = {0.f,0.f,0.f,0.f,0.f,0.f,0.f,0.f};
    int cur = -1;
    for (int r = r0 + rh; r < r1; r += 16) {
        int g = batch[r];
        if (g != cur) {
            if (cur >= 0) {
#pragma unroll
                for (int j = 0; j < 8; ++j)
                    atomicAdd(&pooled[cur * 128 + c * 8 + j], acc[j]);
            }
#pragma unroll
            for (int j = 0; j < 8; ++j) acc[j] = 0.f;
            cur = g;
        }
        int4 u = B4[(size_t)r * 16 + c];
        float f[8] = { bflo(u.x), bfhi(u.x), bflo(u.y), bfhi(u.y),
                       bflo(u.z), bfhi(u.z), bflo(u.w), bfhi(u.w) };
#pragma unroll
        for (int j = 0; j < 8; ++j) acc[j] += fmaxf(fmaf(f[j], sc[j], sh[j]), 0.f);
    }
    if (cur >= 0) {
#pragma unroll
        for (int j = 0; j < 8; ++j)
            atomicAdd(&pooled[cur * 128 + c * 8 + j], acc[j]);
    }
}

// ---------- FC ----------
__global__ __launch_bounds__(256) void k_fc(const float* __restrict__ pooled,
                                            const int* __restrict__ gcnt,
                                            const float* __restrict__ Wfc,
                                            const float* __restrict__ bfc,
                                            float* __restrict__ out) {
    int idx = blockIdx.x * 256 + threadIdx.x;
    if (idx >= 64 * 32) return;
    int g = idx >> 5, o = idx & 31;
    float inv = 1.f / fmaxf((float)gcnt[g], 1.f);
    float acc = bfc[o];
    for (int k = 0; k < 128; ++k)
        acc = fmaf(pooled[g * 128 + k] * inv, Wfc[k * 32 + o], acc);
    out[idx] = acc;
}

extern "C" void kernel_launch(void* const* d_in, const int* in_sizes, int n_in,
                              void* d_out, int out_size, void* d_ws, size_t ws_size,
                              hipStream_t stream) {
    const float* x    = (const float*)d_in[0];
    const int*  eidx  = (const int*)d_in[1];
    const int*  batch = (const int*)d_in[2];
    const float* W0 = (const float*)d_in[3];
    const float* b0 = (const float*)d_in[4];
    const float* g0 = (const float*)d_in[5];
    const float* be0 = (const float*)d_in[6];
    const float* W1 = (const float*)d_in[7];
    const float* b1 = (const float*)d_in[8];
    const float* g1 = (const float*)d_in[9];
    const float* be1 = (const float*)d_in[10];
    const float* Wfc = (const float*)d_in[11];
    const float* bfc = (const float*)d_in[12];
    float* out = (float*)d_out;

    const int N = in_sizes[0] / 128;
    const int E = in_sizes[1] / 2;
    const int* esrc = eidx;
    const int* edst = eidx + E;
    const int NB = (N + 255) >> 8;               // buckets of 256 nodes (<=512)
    const size_t paddedE = (size_t)E + 7 * (size_t)N;

    // ---- workspace carve-up ----
    char* base = (char*)d_ws;
    size_t off = 0;
    auto take = [&](size_t bytes) -> char* {
        char* p = base + off;
        off = (off + bytes + 255) & ~(size_t)255;
        return p;
    };
    unsigned short* hA = (unsigned short*)take((size_t)N * 128 * 2); // bf16 h; aliased as rec
    int2* rec = (int2*)hA;                                           // bucket records (dead before gemm1)
    unsigned* B = (unsigned*)take((size_t)N * 64 * 4);               // bf16-packed agg buffer
    int2* csr   = (int2*)take(paddedE * 8);
    int* rowptr = (int*)take((size_t)N * 4);
    int* deg    = (int*)take((size_t)N * 4);
    float* dinv = (float*)take((size_t)N * 4);
    int* counts = (int*)take((size_t)512 * NBLK * 4);                // 1 MB
    int* total  = (int*)take(512 * 4);
    int* bbase  = (int*)take(512 * 4);
    int* part   = (int*)take(1024 * 4);
    unsigned short* W0t = (unsigned short*)take(16384 * 2);
    unsigned short* W1t = (unsigned short*)take(16384 * 2);
    float* P1 = (float*)take((size_t)NSTAT * 128 * 4);
    float* P2 = (float*)take((size_t)NSTAT * 128 * 4);
    char* zeroB0 = base + off;
    float* pooled = (float*)take(64 * 128 * 4);
    int*   gcnt   = (int*)take(64 * 4);
    size_t zeroB_bytes = (size_t)((base + off) - zeroB0);
    float* scale1 = (float*)take(128 * 4);
    float* shift1 = (float*)take(128 * 4);
    float* scale2 = (float*)take(128 * 4);
    float* shift2 = (float*)take(128 * 4);
    (void)ws_size; (void)n_in; (void)out_size;

    hipMemsetAsync(zeroB0, 0, zeroB_bytes, stream);
    hipMemsetAsync(csr, 0, paddedE * 8, stream);   // pad entries -> {src=0, w=0}

    // weight prep (tiny)
    k_wprep<<<8, 256, 0, stream>>>(W0, W0t);
    k_wprep<<<8, 256, 0, stream>>>(W1, W1t);

    // ---- bucketed CSR build (deterministic, no global atomics) ----
    const int CH256 = (E + NBLK - 1) / NBLK;
    kb_count<<<NBLK, 256, 0, stream>>>(edst, E, NB, CH256, counts);
    kb_offsets<<<NB, NBLK, 0, stream>>>(counts, total);
    kb_base<<<1, 512, 0, stream>>>(total, NB, bbase);
    kb_scatter<<<NBLK, NBLK, 0, stream>>>(esrc, edst, E, NB, CH256, counts, bbase, rec);
    kb_deg<<<NB, 256, 0, stream>>>(rec, bbase, total, deg, N);
    k_dinv<<<(N + 255) / 256, 256, 0, stream>>>(deg, N, dinv);
    const int nbScan = (N + 1023) / 1024;
    k_scan_part<<<nbScan, 256, 0, stream>>>(deg, N, part);
    k_scan_mid<<<1, 64, 0, stream>>>(part, nbScan);
    k_scan_final<<<nbScan, 256, 0, stream>>>(deg, N, part, rowptr);
    kb_place<<<NB, 256, 0, stream>>>(rec, bbase, total, rowptr, dinv, csr, N);

    const int gGemm = (N + 63) / 64;
    const int gAgg  = (N + 3) / 4;
    const float invN = 1.0f / (float)N;

    // layer 1
    k_gemm<<<gGemm, 256, 0, stream>>>(x, W0t, scale1, shift1, hA, N, 0);
    k_agg<<<gAgg, 256, 0, stream>>>(hA, rowptr, deg, csr, dinv, b0, B, N);
    k_stats<<<NSTAT, 256, 0, stream>>>((const int4*)B, N, P1, P2);
    k_bnfinal<<<1, 256, 0, stream>>>(P1, P2, g0, be0, scale1, shift1, invN);

    // layer 2 (BN1+ReLU fused into GEMM2's staging)
    k_gemm<<<gGemm, 256, 0, stream>>>(B, W1t, scale1, shift1, hA, N, 1);
    k_agg<<<gAgg, 256, 0, stream>>>(hA, rowptr, deg, csr, dinv, b1, B, N);
    k_stats<<<NSTAT, 256, 0, stream>>>((const int4*)B, N, P1, P2);
    k_bnfinal<<<1, 256, 0, stream>>>(P1, P2, g1, be1, scale2, shift2, invN);

    // pool (BN2+ReLU fused) + FC
    k_hist<<<256, 256, 0, stream>>>(batch, N, gcnt);
    const int rpb = (N + 511) / 512;
    k_pool<<<(N + rpb - 1) / rpb, 256, 0, stream>>>((const int4*)B, scale2, shift2, batch, N, rpb, pooled);
    k_fc<<<8, 256, 0, stream>>>(pooled, gcnt, Wfc, bfc, out);
}

// Round 6
// 452.007 us; speedup vs baseline: 2.4211x; 1.0272x over previous
//
#include <hip/hip_runtime.h>

typedef short bf16x8 __attribute__((ext_vector_type(8)));
typedef float f32x4 __attribute__((ext_vector_type(4)));

#define NBLK 512   // scatter blocks (fixed for deterministic two-level offsets)
#define NSTAT 512  // stats partial blocks

// ---------- bf16 helpers ----------
__device__ __forceinline__ unsigned short f2bf(float f) {
    unsigned u = __float_as_uint(f);
    u += 0x7fffu + ((u >> 16) & 1u);   // round-to-nearest-even
    return (unsigned short)(u >> 16);
}
__device__ __forceinline__ float bflo(unsigned u) { return __uint_as_float(u << 16); }
__device__ __forceinline__ float bfhi(unsigned u) { return __uint_as_float(u & 0xffff0000u); }

// =================== bucketed CSR build (bucket = dst>>8; zero global atomics) ===================

__global__ __launch_bounds__(256) void kb_count(const int* __restrict__ dst, int E, int nb,
                                                int chunk, int* __restrict__ counts) {
    __shared__ int h[512];
    for (int i = threadIdx.x; i < 512; i += 256) h[i] = 0;
    __syncthreads();
    int e0 = blockIdx.x * chunk, e1 = min(e0 + chunk, E);
    for (int e = e0 + threadIdx.x; e < e1; e += 256) atomicAdd(&h[dst[e] >> 8], 1);
    __syncthreads();
    for (int b = threadIdx.x; b < nb; b += 256) counts[b * NBLK + blockIdx.x] = h[b];
}

__global__ __launch_bounds__(NBLK) void kb_offsets(int* __restrict__ counts,
                                                   int* __restrict__ total) {
    __shared__ int s[NBLK];
    int b = blockIdx.x, t = threadIdx.x;
    int v = counts[b * NBLK + t];
    s[t] = v; __syncthreads();
    for (int off = 1; off < NBLK; off <<= 1) {
        int x = (t >= off) ? s[t - off] : 0;
        __syncthreads();
        s[t] += x;
        __syncthreads();
    }
    counts[b * NBLK + t] = s[t] - v;          // exclusive
    if (t == NBLK - 1) total[b] = s[t];
}

__global__ __launch_bounds__(512) void kb_base(const int* __restrict__ total, int nb,
                                               int* __restrict__ bbase) {
    __shared__ int s[512];
    int t = threadIdx.x;
    int v = (t < nb) ? total[t] : 0;
    s[t] = v; __syncthreads();
    for (int off = 1; off < 512; off <<= 1) {
        int x = (t >= off) ? s[t - off] : 0;
        __syncthreads();
        s[t] += x;
        __syncthreads();
    }
    if (t < nb) bbase[t] = s[t] - v;
}

__global__ __launch_bounds__(NBLK) void kb_scatter(const int* __restrict__ src,
                                                   const int* __restrict__ dst, int E, int nb,
                                                   int chunk,
                                                   const int* __restrict__ counts,
                                                   const int* __restrict__ bbase,
                                                   int2* __restrict__ rec) {
    __shared__ int cur[512];
    int t = threadIdx.x;
    if (t < nb) cur[t] = bbase[t] + counts[t * NBLK + blockIdx.x];
    __syncthreads();
    int e0 = blockIdx.x * chunk, e1 = min(e0 + chunk, E);
    for (int e = e0 + t; e < e1; e += NBLK) {
        int s = src[e], d = dst[e];
        int pos = atomicAdd(&cur[d >> 8], 1);
        rec[pos] = make_int2(s, d);
    }
}

// per-bucket degree count via LDS (+ fused dinv)
__global__ __launch_bounds__(256) void kb_deg(const int2* __restrict__ rec,
                                              const int* __restrict__ bbase,
                                              const int* __restrict__ total,
                                              int* __restrict__ deg,
                                              float* __restrict__ dinv, int N) {
    __shared__ int dc[256];
    int b = blockIdx.x, t = threadIdx.x;
    dc[t] = 0; __syncthreads();
    int r0 = bbase[b], r1 = r0 + total[b];
    for (int i = r0 + t; i < r1; i += 256) atomicAdd(&dc[rec[i].y & 255], 1);
    __syncthreads();
    int gn = b * 256 + t;
    if (gn < N) {
        int d = dc[t];
        deg[gn] = d;
        dinv[gn] = rsqrtf((float)(d + 1));
    }
}

// ---------- 3-kernel exclusive scan of PADDED deg -> rowptr ----------
__global__ __launch_bounds__(256) void k_scan_part(const int* __restrict__ deg, int N,
                                                   int* __restrict__ part) {
    int base = blockIdx.x * 1024 + threadIdx.x * 4;
    int s = 0;
#pragma unroll
    for (int i = 0; i < 4; ++i) {
        int idx = base + i;
        if (idx < N) s += (deg[idx] + 7) & ~7;
    }
    __shared__ int red[256];
    red[threadIdx.x] = s; __syncthreads();
    for (int off = 128; off > 0; off >>= 1) {
        if (threadIdx.x < off) red[threadIdx.x] += red[threadIdx.x + off];
        __syncthreads();
    }
    if (threadIdx.x == 0) part[blockIdx.x] = red[0];
}
__global__ void k_scan_mid(int* part, int nb) {
    if (threadIdx.x == 0 && blockIdx.x == 0) {
        int run = 0;
        for (int i = 0; i < nb; ++i) { int t = part[i]; part[i] = run; run += t; }
    }
}
__global__ __launch_bounds__(256) void k_scan_final(const int* __restrict__ deg, int N,
                                                    const int* __restrict__ part,
                                                    int* __restrict__ rowptr) {
    int t = threadIdx.x;
    int base = blockIdx.x * 1024 + t * 4;
    int v[4]; int s = 0;
#pragma unroll
    for (int i = 0; i < 4; ++i) {
        int idx = base + i;
        v[i] = (idx < N) ? ((deg[idx] + 7) & ~7) : 0;
        s += v[i];
    }
    __shared__ int sc[256];
    sc[t] = s; __syncthreads();
    for (int off = 1; off < 256; off <<= 1) {
        int x = (t >= off) ? sc[t - off] : 0;
        __syncthreads();
        sc[t] += x;
        __syncthreads();
    }
    int excl = sc[t] - s + part[blockIdx.x];
#pragma unroll
    for (int i = 0; i < 4; ++i) {
        int idx = base + i;
        if (idx < N) { rowptr[idx] = excl; excl += v[i]; }
    }
}

// per-bucket CSR placement via LDS cursors; writes pad entries itself (no csr memset)
__global__ __launch_bounds__(256) void kb_place(const int2* __restrict__ rec,
                                                const int* __restrict__ bbase,
                                                const int* __restrict__ total,
                                                const int* __restrict__ rowptr,
                                                const float* __restrict__ dinv,
                                                int2* __restrict__ csr, int N) {
    __shared__ int cur[256];
    int b = blockIdx.x, t = threadIdx.x;
    int gn = b * 256 + t;
    int rp = (gn < N) ? rowptr[gn] : 0;
    cur[t] = rp;
    __syncthreads();
    int r0 = bbase[b], r1 = r0 + total[b];
    for (int i = r0 + t; i < r1; i += 256) {
        int2 rc = rec[i];
        int pos = atomicAdd(&cur[rc.y & 255], 1);
        float w = dinv[rc.x] * dinv[rc.y];
        csr[pos] = make_int2(rc.x, __float_as_int(w));
    }
    __syncthreads();
    if (gn < N) {
        int end = cur[t];                       // rowptr + deg
        int pe = rp + ((end - rp + 7) & ~7);    // rowptr + padded deg
        for (int i = end; i < pe; ++i) csr[i] = make_int2(0, 0);  // {src=0, w=0}
    }
}

// =================== W prep: bf16 A-fragment layout (both weights, one launch) ===================
__global__ __launch_bounds__(256) void k_wprep(const float* __restrict__ W0,
                                               const float* __restrict__ W1,
                                               unsigned short* __restrict__ W0t,
                                               unsigned short* __restrict__ W1t) {
    int tt = blockIdx.x * 256 + threadIdx.x;   // 4096 = 2 * 32 frags * 64 lanes
    const float* W = (tt < 2048) ? W0 : W1;
    unsigned short* Wt = (tt < 2048) ? W0t : W1t;
    int t = tt & 2047;
    int f = t >> 6, lane = t & 63;
    int kc = f >> 3, nt = f & 7;
    int kbase = kc * 32 + (lane >> 4) * 8;
    int n = nt * 16 + (lane & 15);
    unsigned short t8[8];
#pragma unroll
    for (int j = 0; j < 8; ++j) t8[j] = f2bf(W[(size_t)(kbase + j) * 128 + n]);
    unsigned short* o = &Wt[(size_t)t * 8];
    *(ushort4*)&o[0] = *(ushort4*)&t8[0];
    *(ushort4*)&o[4] = *(ushort4*)&t8[4];
}

// =================== MFMA GEMM: Hout(bf16) = act(X) @ W ===================
__global__ __launch_bounds__(256) void k_gemm(const void* __restrict__ Xv,
                                              const unsigned short* __restrict__ Wt,
                                              const float* __restrict__ scale,
                                              const float* __restrict__ shift,
                                              unsigned short* __restrict__ Hout,
                                              int N, int xbf16) {
    __shared__ unsigned short sX[64 * 136];
    const int tid = threadIdx.x;
    const int rowBase = blockIdx.x * 64;

    if (!xbf16) {
        const float* X = (const float*)Xv;
#pragma unroll
        for (int i = 0; i < 8; ++i) {
            int f4 = tid + 256 * i;
            int r = f4 >> 5; int k4 = (f4 & 31) * 4;
            int gr = rowBase + r;
            float4 v = make_float4(0.f, 0.f, 0.f, 0.f);
            if (gr < N) v = *(const float4*)&X[(size_t)gr * 128 + k4];
            ushort4 p;
            p.x = f2bf(v.x); p.y = f2bf(v.y); p.z = f2bf(v.z); p.w = f2bf(v.w);
            *(ushort4*)&sX[r * 136 + k4] = p;
        }
    } else {
        const int4* X = (const int4*)Xv;
#pragma unroll
        for (int i = 0; i < 4; ++i) {
            int f8 = tid + 256 * i;
            int r = f8 >> 4; int k8 = (f8 & 15) * 8;
            int gr = rowBase + r;
            int4 u = make_int4(0, 0, 0, 0);
            if (gr < N) u = X[(size_t)gr * 16 + (f8 & 15)];
            float fv[8] = { bflo(u.x), bfhi(u.x), bflo(u.y), bfhi(u.y),
                            bflo(u.z), bfhi(u.z), bflo(u.w), bfhi(u.w) };
            unsigned short t8[8];
#pragma unroll
            for (int j = 0; j < 8; ++j)
                t8[j] = f2bf(fmaxf(fmaf(fv[j], scale[k8 + j], shift[k8 + j]), 0.f));
            *(ushort4*)&sX[r * 136 + k8]     = *(ushort4*)&t8[0];
            *(ushort4*)&sX[r * 136 + k8 + 4] = *(ushort4*)&t8[4];
        }
    }
    __syncthreads();

    const int lane = tid & 63, wave = tid >> 6;
    const int m = lane & 15, q = lane >> 4;
    const int rowOff = (wave * 16 + m) * 136 + q * 8;
    f32x4 acc[8];
#pragma unroll
    for (int nt = 0; nt < 8; ++nt) acc[nt] = (f32x4){0.f, 0.f, 0.f, 0.f};
    const bf16x8* WtF = (const bf16x8*)Wt;
#pragma unroll
    for (int kc = 0; kc < 4; ++kc) {
        bf16x8 xb = *(const bf16x8*)&sX[rowOff + kc * 32];
#pragma unroll
        for (int nt = 0; nt < 8; ++nt) {
            bf16x8 wa = WtF[(kc * 8 + nt) * 64 + lane];
            acc[nt] = __builtin_amdgcn_mfma_f32_16x16x32_bf16(wa, xb, acc[nt], 0, 0, 0);
        }
    }
    int grow = rowBase + wave * 16 + m;
    if (grow < N) {
#pragma unroll
        for (int nt = 0; nt < 8; ++nt) {
            ushort4 p;
            p.x = f2bf(acc[nt][0]); p.y = f2bf(acc[nt][1]);
            p.z = f2bf(acc[nt][2]); p.w = f2bf(acc[nt][3]);
            *(ushort4*)&Hout[(size_t)grow * 128 + nt * 16 + q * 4] = p;
        }
    }
}

// =================== aggregation: pad-8 layout, 16-deep dual-group unroll ===================
__global__ __launch_bounds__(256) void k_agg(const unsigned short* __restrict__ H,
                                             const int* __restrict__ rowptr,
                                             const int* __restrict__ deg,
                                             const int2* __restrict__ csr,
                                             const float* __restrict__ dinv,
                                             const float* __restrict__ bias,
                                             unsigned* __restrict__ out, int N) {
    int wave = threadIdx.x >> 6;
    int lane = threadIdx.x & 63;
    int node = blockIdx.x * 4 + wave;
    if (node >= N) return;
    const unsigned* Hu = (const unsigned*)H;
    int start = rowptr[node];
    int pd = (deg[node] + 7) & ~7;
    float a0 = 0.f, a1 = 0.f;
    const int4* cp = (const int4*)(csr + start);
    int j = 0;
    for (; j + 16 <= pd; j += 16) {
        int4 q0 = cp[0], q1 = cp[1], q2 = cp[2], q3 = cp[3];
        int4 q4 = cp[4], q5 = cp[5], q6 = cp[6], q7 = cp[7];
        cp += 8;
        unsigned u0 = Hu[(size_t)q0.x * 64 + lane];
        unsigned u1 = Hu[(size_t)q0.z * 64 + lane];
        unsigned u2 = Hu[(size_t)q1.x * 64 + lane];
        unsigned u3 = Hu[(size_t)q1.z * 64 + lane];
        unsigned u4 = Hu[(size_t)q2.x * 64 + lane];
        unsigned u5 = Hu[(size_t)q2.z * 64 + lane];
        unsigned u6 = Hu[(size_t)q3.x * 64 + lane];
        unsigned u7 = Hu[(size_t)q3.z * 64 + lane];
        unsigned u8 = Hu[(size_t)q4.x * 64 + lane];
        unsigned u9 = Hu[(size_t)q4.z * 64 + lane];
        unsigned uA = Hu[(size_t)q5.x * 64 + lane];
        unsigned uB = Hu[(size_t)q5.z * 64 + lane];
        unsigned uC = Hu[(size_t)q6.x * 64 + lane];
        unsigned uD = Hu[(size_t)q6.z * 64 + lane];
        unsigned uE = Hu[(size_t)q7.x * 64 + lane];
        unsigned uF = Hu[(size_t)q7.z * 64 + lane];
        float w0 = __int_as_float(q0.y), w1 = __int_as_float(q0.w);
        float w2 = __int_as_float(q1.y), w3 = __int_as_float(q1.w);
        float w4 = __int_as_float(q2.y), w5 = __int_as_float(q2.w);
        float w6 = __int_as_float(q3.y), w7 = __int_as_float(q3.w);
        float w8 = __int_as_float(q4.y), w9 = __int_as_float(q4.w);
        float wA = __int_as_float(q5.y), wB = __int_as_float(q5.w);
        float wC = __int_as_float(q6.y), wD = __int_as_float(q6.w);
        float wE = __int_as_float(q7.y), wF = __int_as_float(q7.w);
        a0 = fmaf(w0, bflo(u0), a0); a1 = fmaf(w0, bfhi(u0), a1);
        a0 = fmaf(w1, bflo(u1), a0); a1 = fmaf(w1, bfhi(u1), a1);
        a0 = fmaf(w2, bflo(u2), a0); a1 = fmaf(w2, bfhi(u2), a1);
        a0 = fmaf(w3, bflo(u3), a0); a1 = fmaf(w3, bfhi(u3), a1);
        a0 = fmaf(w4, bflo(u4), a0); a1 = fmaf(w4, bfhi(u4), a1);
        a0 = fmaf(w5, bflo(u5), a0); a1 = fmaf(w5, bfhi(u5), a1);
        a0 = fmaf(w6, bflo(u6), a0); a1 = fmaf(w6, bfhi(u6), a1);
        a0 = fmaf(w7, bflo(u7), a0); a1 = fmaf(w7, bfhi(u7), a1);
        a0 = fmaf(w8, bflo(u8), a0); a1 = fmaf(w8, bfhi(u8), a1);
        a0 = fmaf(w9, bflo(u9), a0); a1 = fmaf(w9, bfhi(u9), a1);
        a0 = fmaf(wA, bflo(uA), a0); a1 = fmaf(wA, bfhi(uA), a1);
        a0 = fmaf(wB, bflo(uB), a0); a1 = fmaf(wB, bfhi(uB), a1);
        a0 = fmaf(wC, bflo(uC), a0); a1 = fmaf(wC, bfhi(uC), a1);
        a0 = fmaf(wD, bflo(uD), a0); a1 = fmaf(wD, bfhi(uD), a1);
        a0 = fmaf(wE, bflo(uE), a0); a1 = fmaf(wE, bfhi(uE), a1);
        a0 = fmaf(wF, bflo(uF), a0); a1 = fmaf(wF, bfhi(uF), a1);
    }
    if (j < pd) {   // remaining group of 8
        int4 q0 = cp[0], q1 = cp[1], q2 = cp[2], q3 = cp[3];
        unsigned u0 = Hu[(size_t)q0.x * 64 + lane];
        unsigned u1 = Hu[(size_t)q0.z * 64 + lane];
        unsigned u2 = Hu[(size_t)q1.x * 64 + lane];
        unsigned u3 = Hu[(size_t)q1.z * 64 + lane];
        unsigned u4 = Hu[(size_t)q2.x * 64 + lane];
        unsigned u5 = Hu[(size_t)q2.z * 64 + lane];
        unsigned u6 = Hu[(size_t)q3.x * 64 + lane];
        unsigned u7 = Hu[(size_t)q3.z * 64 + lane];
        float w0 = __int_as_float(q0.y), w1 = __int_as_float(q0.w);
        float w2 = __int_as_float(q1.y), w3 = __int_as_float(q1.w);
        float w4 = __int_as_float(q2.y), w5 = __int_as_float(q2.w);
        float w6 = __int_as_float(q3.y), w7 = __int_as_float(q3.w);
        a0 = fmaf(w0, bflo(u0), a0); a1 = fmaf(w0, bfhi(u0), a1);
        a0 = fmaf(w1, bflo(u1), a0); a1 = fmaf(w1, bfhi(u1), a1);
        a0 = fmaf(w2, bflo(u2), a0); a1 = fmaf(w2, bfhi(u2), a1);
        a0 = fmaf(w3, bflo(u3), a0); a1 = fmaf(w3, bfhi(u3), a1);
        a0 = fmaf(w4, bflo(u4), a0); a1 = fmaf(w4, bfhi(u4), a1);
        a0 = fmaf(w5, bflo(u5), a0); a1 = fmaf(w5, bfhi(u5), a1);
        a0 = fmaf(w6, bflo(u6), a0); a1 = fmaf(w6, bfhi(u6), a1);
        a0 = fmaf(w7, bflo(u7), a0); a1 = fmaf(w7, bfhi(u7), a1);
    }
    { // self loop
        float dn = dinv[node];
        float w = dn * dn;
        unsigned u = Hu[(size_t)node * 64 + lane];
        a0 = fmaf(w, bflo(u), a0);
        a1 = fmaf(w, bfhi(u), a1);
    }
    float2 bv = ((const float2*)bias)[lane];
    a0 += bv.x; a1 += bv.y;
    out[(size_t)node * 64 + lane] = (unsigned)f2bf(a0) | ((unsigned)f2bf(a1) << 16);
}

// ---------- BN column stats: int4 loads, shuffle-reduce, per-block partials ----------
__global__ __launch_bounds__(256) void k_stats(const int4* __restrict__ B4, int N,
                                               float* __restrict__ P1,
                                               float* __restrict__ P2) {
    int tid = threadIdx.x;
    int lane = tid & 63, wave = tid >> 6;
    int c = lane & 15;
    int rsub = lane >> 4;
    float s1[8] = {0.f,0.f,0.f,0.f,0.f,0.f,0.f,0.f};
    float s2[8] = {0.f,0.f,0.f,0.f,0.f,0.f,0.f,0.f};
    for (int r = blockIdx.x * 16 + wave * 4 + rsub; r < N; r += NSTAT * 16) {
        int4 u = B4[(size_t)r * 16 + c];
        float f[8] = { bflo(u.x), bfhi(u.x), bflo(u.y), bfhi(u.y),
                       bflo(u.z), bfhi(u.z), bflo(u.w), bfhi(u.w) };
#pragma unroll
        for (int j = 0; j < 8; ++j) { s1[j] += f[j]; s2[j] = fmaf(f[j], f[j], s2[j]); }
    }
#pragma unroll
    for (int j = 0; j < 8; ++j) {
        s1[j] += __shfl_xor(s1[j], 16, 64);
        s1[j] += __shfl_xor(s1[j], 32, 64);
        s2[j] += __shfl_xor(s2[j], 16, 64);
        s2[j] += __shfl_xor(s2[j], 32, 64);
    }
    __shared__ float ls1[4][128], ls2[4][128];
    if (rsub == 0) {
#pragma unroll
        for (int j = 0; j < 8; ++j) { ls1[wave][c * 8 + j] = s1[j]; ls2[wave][c * 8 + j] = s2[j]; }
    }
    __syncthreads();
    if (tid < 128) {
        P1[blockIdx.x * 128 + tid] = ls1[0][tid] + ls1[1][tid] + ls1[2][tid] + ls1[3][tid];
        P2[blockIdx.x * 128 + tid] = ls2[0][tid] + ls2[1][tid] + ls2[2][tid] + ls2[3][tid];
    }
}

__global__ __launch_bounds__(256) void k_bnfinal(const float* __restrict__ P1,
                          const float* __restrict__ P2,
                          const float* __restrict__ g, const float* __restrict__ be,
                          float* __restrict__ scale, float* __restrict__ shift,
                          float invN) {
    __shared__ float sm[256];
    int t = threadIdx.x;
    int c = t & 127;
    const float* P = (t < 128) ? P1 : P2;
    float s = 0.f;
    for (int b = 0; b < NSTAT; ++b) s += P[b * 128 + c];
    sm[t] = s;
    __syncthreads();
    if (t < 128) {
        float mu = sm[t] * invN;
        float var = sm[t + 128] * invN - mu * mu;
        float sc = g[t] * rsqrtf(var + 1e-5f);
        scale[t] = sc;
        shift[t] = fmaf(-mu, sc, be[t]);
    }
}

// ---------- per-graph histogram of batch ----------
__global__ __launch_bounds__(256) void k_hist(const int* __restrict__ batch, int N,
                                              int* __restrict__ gcnt) {
    __shared__ int h[64];
    if (threadIdx.x < 64) h[threadIdx.x] = 0;
    __syncthreads();
    for (int i = blockIdx.x * 256 + threadIdx.x; i < N; i += gridDim.x * 256)
        atomicAdd(&h[batch[i]], 1);
    __syncthreads();
    if (threadIdx.x < 64 && h[threadIdx.x]) atomicAdd(&gcnt[threadIdx.x], h[threadIdx.x]);
}

// ---------- pool: int4 loads, 16 row-walkers x 8 features ----------
__global__ __launch_bounds__(256) void k_pool(const int4* __restrict__ B4,
                                              const float* __restrict__ scale,
                                              const float* __restrict__ shift,
                                              const int* __restrict__ batch, int N,
                                              int rpb, float* __restrict__ pooled) {
    int tid = threadIdx.x;
    int c = tid & 15;
    int rh = tid >> 4;
    int r0 = blockIdx.x * rpb;
    int r1 = min(r0 + rpb, N);
    float sc[8], sh[8];
#pragma unroll
    for (int j = 0; j < 8; ++j) { sc[j] = scale[c * 8 + j]; sh[j] = shift[c * 8 + j]; }
    float acc[8] = {0.f,0.f,0.f,0.f,0.f,0.f,0.f,0.f};
    int cur = -1;
    for (int r = r0 + rh; r < r1; r += 16) {
        int g = batch[r];
        if (g != cur) {
            if (cur >= 0) {
#pragma unroll
                for (int j = 0; j < 8; ++j)
                    atomicAdd(&pooled[cur * 128 + c * 8 + j], acc[j]);
            }
#pragma unroll
            for (int j = 0; j < 8; ++j) acc[j] = 0.f;
            cur = g;
        }
        int4 u = B4[(size_t)r * 16 + c];
        float f[8] = { bflo(u.x), bfhi(u.x), bflo(u.y), bfhi(u.y),
                       bflo(u.z), bfhi(u.z), bflo(u.w), bfhi(u.w) };
#pragma unroll
        for (int j = 0; j < 8; ++j) acc[j] += fmaxf(fmaf(f[j], sc[j], sh[j]), 0.f);
    }
    if (cur >= 0) {
#pragma unroll
        for (int j = 0; j < 8; ++j)
            atomicAdd(&pooled[cur * 128 + c * 8 + j], acc[j]);
    }
}

// ---------- FC ----------
__global__ __launch_bounds__(256) void k_fc(const float* __restrict__ pooled,
                                            const int* __restrict__ gcnt,
                                            const float* __restrict__ Wfc,
                                            const float* __restrict__ bfc,
                                            float* __restrict__ out) {
    int idx = blockIdx.x * 256 + threadIdx.x;
    if (idx >= 64 * 32) return;
    int g = idx >> 5, o = idx & 31;
    float inv = 1.f / fmaxf((float)gcnt[g], 1.f);
    float acc = bfc[o];
    for (int k = 0; k < 128; ++k)
        acc = fmaf(pooled[g * 128 + k] * inv, Wfc[k * 32 + o], acc);
    out[idx] = acc;
}

extern "C" void kernel_launch(void* const* d_in, const int* in_sizes, int n_in,
                              void* d_out, int out_size, void* d_ws, size_t ws_size,
                              hipStream_t stream) {
    const float* x    = (const float*)d_in[0];
    const int*  eidx  = (const int*)d_in[1];
    const int*  batch = (const int*)d_in[2];
    const float* W0 = (const float*)d_in[3];
    const float* b0 = (const float*)d_in[4];
    const float* g0 = (const float*)d_in[5];
    const float* be0 = (const float*)d_in[6];
    const float* W1 = (const float*)d_in[7];
    const float* b1 = (const float*)d_in[8];
    const float* g1 = (const float*)d_in[9];
    const float* be1 = (const float*)d_in[10];
    const float* Wfc = (const float*)d_in[11];
    const float* bfc = (const float*)d_in[12];
    float* out = (float*)d_out;

    const int N = in_sizes[0] / 128;
    const int E = in_sizes[1] / 2;
    const int* esrc = eidx;
    const int* edst = eidx + E;
    const int NB = (N + 255) >> 8;               // buckets of 256 nodes (<=512)
    const size_t paddedE = (size_t)E + 7 * (size_t)N;

    // ---- workspace carve-up ----
    char* base = (char*)d_ws;
    size_t off = 0;
    auto take = [&](size_t bytes) -> char* {
        char* p = base + off;
        off = (off + bytes + 255) & ~(size_t)255;
        return p;
    };
    unsigned short* hA = (unsigned short*)take((size_t)N * 128 * 2); // bf16 h; aliased as rec
    int2* rec = (int2*)hA;                                           // bucket records (dead before gemm1)
    unsigned* B = (unsigned*)take((size_t)N * 64 * 4);               // bf16-packed agg buffer
    int2* csr   = (int2*)take(paddedE * 8);
    int* rowptr = (int*)take((size_t)N * 4);
    int* deg    = (int*)take((size_t)N * 4);
    float* dinv = (float*)take((size_t)N * 4);
    int* counts = (int*)take((size_t)512 * NBLK * 4);                // 1 MB
    int* total  = (int*)take(512 * 4);
    int* bbase  = (int*)take(512 * 4);
    int* part   = (int*)take(1024 * 4);
    unsigned short* W0t = (unsigned short*)take(16384 * 2);
    unsigned short* W1t = (unsigned short*)take(16384 * 2);
    float* P1 = (float*)take((size_t)NSTAT * 128 * 4);
    float* P2 = (float*)take((size_t)NSTAT * 128 * 4);
    char* zeroB0 = base + off;
    float* pooled = (float*)take(64 * 128 * 4);
    int*   gcnt   = (int*)take(64 * 4);
    size_t zeroB_bytes = (size_t)((base + off) - zeroB0);
    float* scale1 = (float*)take(128 * 4);
    float* shift1 = (float*)take(128 * 4);
    float* scale2 = (float*)take(128 * 4);
    float* shift2 = (float*)take(128 * 4);
    (void)ws_size; (void)n_in; (void)out_size;

    hipMemsetAsync(zeroB0, 0, zeroB_bytes, stream);

    // weight prep (both, one launch)
    k_wprep<<<16, 256, 0, stream>>>(W0, W1, W0t, W1t);

    // ---- bucketed CSR build (deterministic, no global atomics) ----
    const int CH256 = (E + NBLK - 1) / NBLK;
    kb_count<<<NBLK, 256, 0, stream>>>(edst, E, NB, CH256, counts);
    kb_offsets<<<NB, NBLK, 0, stream>>>(counts, total);
    kb_base<<<1, 512, 0, stream>>>(total, NB, bbase);
    kb_scatter<<<NBLK, NBLK, 0, stream>>>(esrc, edst, E, NB, CH256, counts, bbase, rec);
    kb_deg<<<NB, 256, 0, stream>>>(rec, bbase, total, deg, dinv, N);
    const int nbScan = (N + 1023) / 1024;
    k_scan_part<<<nbScan, 256, 0, stream>>>(deg, N, part);
    k_scan_mid<<<1, 64, 0, stream>>>(part, nbScan);
    k_scan_final<<<nbScan, 256, 0, stream>>>(deg, N, part, rowptr);
    kb_place<<<NB, 256, 0, stream>>>(rec, bbase, total, rowptr, dinv, csr, N);

    const int gGemm = (N + 63) / 64;
    const int gAgg  = (N + 3) / 4;
    const float invN = 1.0f / (float)N;

    // layer 1
    k_gemm<<<gGemm, 256, 0, stream>>>(x, W0t, scale1, shift1, hA, N, 0);
    k_agg<<<gAgg, 256, 0, stream>>>(hA, rowptr, deg, csr, dinv, b0, B, N);
    k_stats<<<NSTAT, 256, 0, stream>>>((const int4*)B, N, P1, P2);
    k_bnfinal<<<1, 256, 0, stream>>>(P1, P2, g0, be0, scale1, shift1, invN);

    // layer 2 (BN1+ReLU fused into GEMM2's staging)
    k_gemm<<<gGemm, 256, 0, stream>>>(B, W1t, scale1, shift1, hA, N, 1);
    k_agg<<<gAgg, 256, 0, stream>>>(hA, rowptr, deg, csr, dinv, b1, B, N);
    k_stats<<<NSTAT, 256, 0, stream>>>((const int4*)B, N, P1, P2);
    k_bnfinal<<<1, 256, 0, stream>>>(P1, P2, g1, be1, scale2, shift2, invN);

    // pool (BN2+ReLU fused) + FC
    k_hist<<<256, 256, 0, stream>>>(batch, N, gcnt);
    const int rpb = (N + 511) / 512;
    k_pool<<<(N + rpb - 1) / rpb, 256, 0, stream>>>((const int4*)B, scale2, shift2, batch, N, rpb, pooled);
    k_fc<<<8, 256, 0, stream>>>(pooled, gcnt, Wfc, bfc, out);
}